// Round 1
// baseline (10333.184 us; speedup 1.0000x reference)
//
#include <hip/hip_runtime.h>
#include <math.h>

// VSSBlock on MI355X — round 0: fp32 correctness-first implementation.
// B=4, D_MODEL=128, H=W=64, L=4096, D_INNER=256, D_STATE=4, DT_RANK=16.
// Workspace use: ~177 MB (see alloc table in kernel_launch).

#define B_N   4
#define CDM   128   // D_MODEL
#define HH    64
#define WW    64
#define LL    4096  // H*W
#define DI    256   // D_INNER
#define DS    4     // D_STATE
#define DCV   4     // D_CONV (1d causal)
#define DTR   16    // DT_RANK

__device__ __forceinline__ float silu_f(float x) { return x / (1.f + __expf(-x)); }
__device__ __forceinline__ float softplus_f(float x) {
  return (x > 20.f) ? x : log1pf(expf(x));
}
__device__ __forceinline__ float gelu_f(float x) {
  return 0.5f * x * (1.f + erff(x * 0.70710678118654752f));
}

// sequence position t of direction dir  ->  original flat index l (row-major h*W+w).
// Same map is used for gather (build xs) and scatter (combine ys) — verified from
// the reference's flip/untb algebra.
__device__ __forceinline__ int sigma_map(int dir, int t) {
  int tt = (dir & 1) ? (LL - 1 - t) : t;
  if (dir >= 2) tt = ((tt & 63) << 6) | (tt >> 6);  // H=W=64 transpose
  return tt;
}

// ---------------- LN over C=128 with NCHW->(B,L,C) transpose, keeps raw copy ----
__global__ void __launch_bounds__(128) k_ln1(
    const float* __restrict__ x, const float* __restrict__ g,
    const float* __restrict__ be, float* __restrict__ xflat,
    float* __restrict__ x1)
{
  int row = blockIdx.x;                 // b*L + l
  int b = row >> 12; int l = row & (LL - 1);
  int c = threadIdx.x;
  float v = x[((size_t)b * CDM + c) * LL + l];
  __shared__ float red[CDM];
  red[c] = v; __syncthreads();
  #pragma unroll
  for (int s = CDM / 2; s > 0; s >>= 1) { if (c < s) red[c] += red[c + s]; __syncthreads(); }
  float mean = red[0] * (1.f / CDM);
  __syncthreads();
  float dv = v - mean;
  red[c] = dv * dv; __syncthreads();
  #pragma unroll
  for (int s = CDM / 2; s > 0; s >>= 1) { if (c < s) red[c] += red[c + s]; __syncthreads(); }
  float var = red[0] * (1.f / CDM);
  size_t o = (size_t)row * CDM + c;
  xflat[o] = v;
  x1[o] = dv * rsqrtf(var + 1e-5f) * g[c] + be[c];
}

// ---------------- generic row LayerNorm, WIDTH = block size ----------------
template<int WIDTH>
__global__ void __launch_bounds__(WIDTH) k_ln(
    const float* __restrict__ in, const float* __restrict__ g,
    const float* __restrict__ be, float* __restrict__ out)
{
  int row = blockIdx.x;
  int c = threadIdx.x;
  float v = in[(size_t)row * WIDTH + c];
  __shared__ float red[WIDTH];
  red[c] = v; __syncthreads();
  #pragma unroll
  for (int s = WIDTH / 2; s > 0; s >>= 1) { if (c < s) red[c] += red[c + s]; __syncthreads(); }
  float mean = red[0] * (1.f / WIDTH);
  __syncthreads();
  float dv = v - mean;
  red[c] = dv * dv; __syncthreads();
  #pragma unroll
  for (int s = WIDTH / 2; s > 0; s >>= 1) { if (c < s) red[c] += red[c + s]; __syncthreads(); }
  float var = red[0] * (1.f / WIDTH);
  out[(size_t)row * WIDTH + c] = dv * rsqrtf(var + 1e-5f) * g[c] + be[c];
}

// ---------------- generic SGEMM: C(M,N) = A(M,K) @ Wt(N,K)^T ----------------
// 64x64 tile, K-step 16, 256 threads, 4x4 per thread.
// MODE 0: plain store.
// MODE 1: A-rows gathered through sigma_map(dir, t)   (xz GEMM)
// MODE 2: scatter-accumulate C[sigma row] += 0.25*acc (out GEMM -> y_comb)
// MODE 3: C = resid + acc
// MODE 4: C = gelu(acc)
// M, N implied by grid; both must be multiples of 64; K multiple of 16.
template<int MODE>
__global__ void __launch_bounds__(256) k_gemm(
    const float* __restrict__ A, int lda,
    const float* __restrict__ Wt,
    float* __restrict__ C, int ldc, int K,
    int dir, const float* __restrict__ resid)
{
  __shared__ float As[16][65];
  __shared__ float Ws[16][65];
  int tid = threadIdx.x;
  int m0 = blockIdx.x << 6, n0 = blockIdx.y << 6;
  int li = tid >> 2;            // 0..63 tile row
  int lk = (tid & 3) << 2;      // 0,4,8,12
  int tx = tid & 15, ty = tid >> 4;
  float acc[4][4] = {};
  int arow = m0 + li;
  if (MODE == 1) { int b = arow >> 12; int t = arow & (LL - 1); arow = (b << 12) + sigma_map(dir, t); }
  const float* ap = A + (size_t)arow * lda + lk;
  const float* wp = Wt + (size_t)(n0 + li) * K + lk;
  for (int k0 = 0; k0 < K; k0 += 16) {
    float4 av = *(const float4*)(ap + k0);
    float4 wv = *(const float4*)(wp + k0);
    As[lk + 0][li] = av.x; As[lk + 1][li] = av.y; As[lk + 2][li] = av.z; As[lk + 3][li] = av.w;
    Ws[lk + 0][li] = wv.x; Ws[lk + 1][li] = wv.y; Ws[lk + 2][li] = wv.z; Ws[lk + 3][li] = wv.w;
    __syncthreads();
    #pragma unroll
    for (int kk = 0; kk < 16; ++kk) {
      float a0 = As[kk][(ty << 2) + 0], a1 = As[kk][(ty << 2) + 1];
      float a2 = As[kk][(ty << 2) + 2], a3 = As[kk][(ty << 2) + 3];
      float b0 = Ws[kk][(tx << 2) + 0], b1 = Ws[kk][(tx << 2) + 1];
      float b2 = Ws[kk][(tx << 2) + 2], b3 = Ws[kk][(tx << 2) + 3];
      acc[0][0] += a0 * b0; acc[0][1] += a0 * b1; acc[0][2] += a0 * b2; acc[0][3] += a0 * b3;
      acc[1][0] += a1 * b0; acc[1][1] += a1 * b1; acc[1][2] += a1 * b2; acc[1][3] += a1 * b3;
      acc[2][0] += a2 * b0; acc[2][1] += a2 * b1; acc[2][2] += a2 * b2; acc[2][3] += a2 * b3;
      acc[3][0] += a3 * b0; acc[3][1] += a3 * b1; acc[3][2] += a3 * b2; acc[3][3] += a3 * b3;
    }
    __syncthreads();
  }
  #pragma unroll
  for (int r = 0; r < 4; ++r) {
    int row = m0 + (ty << 2) + r;
    int orow = row;
    if (MODE == 2) { int b = row >> 12; int t = row & (LL - 1); orow = (b << 12) + sigma_map(dir, t); }
    #pragma unroll
    for (int q = 0; q < 4; ++q) {
      int col = n0 + (tx << 2) + q;
      size_t off = (size_t)orow * ldc + col;
      float v = acc[r][q];
      if (MODE == 2)      C[off] += 0.25f * v;
      else if (MODE == 3) C[off] = resid[off] + v;
      else if (MODE == 4) C[off] = gelu_f(v);
      else                C[off] = v;
    }
  }
}

// ---------------- depthwise 3x3 conv (NHWC, same pad) + SiLU ----------------
__global__ void __launch_bounds__(256) k_dwconv(
    const float* __restrict__ h, const float* __restrict__ wgt,
    float* __restrict__ out)
{
  int p = blockIdx.x;                 // b*L + l
  int b = p >> 12; int l = p & (LL - 1);
  int hy = l >> 6, wx = l & 63;
  int d = threadIdx.x;
  float acc = 0.f;
  #pragma unroll
  for (int di = -1; di <= 1; ++di) {
    int yy = hy + di; if (yy < 0 || yy >= HH) continue;
    #pragma unroll
    for (int dj = -1; dj <= 1; ++dj) {
      int xx = wx + dj; if (xx < 0 || xx >= WW) continue;
      acc += wgt[d * 9 + (di + 1) * 3 + (dj + 1)] *
             h[(((size_t)b << 12) + (yy << 6) + xx) * DI + d];
    }
  }
  out[(size_t)p * DI + d] = silu_f(acc);
}

// ---------------- causal depthwise conv1d (k=4) + SiLU, reads xm slice of xz ----
__global__ void __launch_bounds__(256) k_conv1d(
    const float* __restrict__ xz, const float* __restrict__ cw,
    const float* __restrict__ cb, float* __restrict__ xmc)
{
  int p = blockIdx.x;                 // b*L + t
  int b = p >> 12; int t = p & (LL - 1);
  int d = threadIdx.x;
  float acc = cb[d];
  #pragma unroll
  for (int k = 0; k < DCV; ++k) {
    int tt = t - (DCV - 1) + k;
    if (tt >= 0)
      acc += cw[d * DCV + k] * xz[((size_t)(b << 12) + tt) * (2 * DI) + d];
  }
  xmc[(size_t)p * DI + d] = silu_f(acc);
}

// ---------------- fused x_proj (24 outputs) + dt projection + softplus --------
// one wave per row. Outputs: dt (B*L,256), xbc (B*L,8) = [B(4) | C(4)].
__global__ void __launch_bounds__(64) k_xproj_dt(
    const float* __restrict__ xmc,
    const float* __restrict__ xw,    // (24,256) this dir
    const float* __restrict__ dtw,   // (256,16) this dir
    const float* __restrict__ dtb,   // (256)    this dir
    float* __restrict__ dtout,
    float* __restrict__ xbc)
{
  int m = blockIdx.x;
  int lane = threadIdx.x;            // 0..63
  float4 xv = *(const float4*)(xmc + (size_t)m * DI + lane * 4);
  float sbuf[24];
  #pragma unroll
  for (int n = 0; n < 24; ++n) {
    float4 wv = *(const float4*)(xw + n * DI + lane * 4);
    float p = xv.x * wv.x + xv.y * wv.y + xv.z * wv.z + xv.w * wv.w;
    #pragma unroll
    for (int o = 1; o < 64; o <<= 1) p += __shfl_xor(p, o);
    sbuf[n] = p;                     // all lanes hold the full reduction
  }
  #pragma unroll
  for (int n = 16; n < 24; ++n)
    if (lane == n - 16) xbc[(size_t)m * 8 + (n - 16)] = sbuf[n];
  #pragma unroll
  for (int j = 0; j < 4; ++j) {
    int np = j * 64 + lane;
    float acc = dtb[np];
    const float* dw = dtw + np * DTR;
    #pragma unroll
    for (int k = 0; k < DTR; ++k) acc += sbuf[k] * dw[k];
    dtout[(size_t)m * DI + np] = softplus_f(acc);
  }
}

// ---------------- selective scan (one direction) -----------------------------
// grid: B * 16 d-chunks of 16; block: 64 threads = 16 d x 4 n.
// h_t = exp(dt*A)*h_{t-1} + dt*B_t*xm_t ; y_t[d] = sum_n h[d,n]*C_t[n]
// y = (y + D*xm) * silu(z)
__global__ void __launch_bounds__(64) k_scan(
    const float* __restrict__ dtbuf, const float* __restrict__ xmc,
    const float* __restrict__ xbc, const float* __restrict__ xz,
    const float* __restrict__ Alog, const float* __restrict__ Dp,
    float* __restrict__ ybuf)
{
  int blk = blockIdx.x;
  int b = blk >> 4; int dc = blk & 15;
  int lane = threadIdx.x;
  int d = (dc << 4) + (lane >> 2);
  int n = lane & 3;
  float Av = -expf(Alog[d * DS + n]);
  float Dv = Dp[d];
  float h = 0.f;
  size_t base = (size_t)b * LL;
  #pragma unroll 4
  for (int t = 0; t < LL; ++t) {
    size_t r = base + t;
    float dt = dtbuf[r * DI + d];
    float xm = xmc[r * DI + d];
    float Bv = xbc[r * 8 + n];
    float Cv = xbc[r * 8 + 4 + n];
    float dA = __expf(dt * Av);
    h = dA * h + dt * Bv * xm;
    float yp = h * Cv;
    yp += __shfl_xor(yp, 1);
    yp += __shfl_xor(yp, 2);
    if (n == 0) {
      float zv = xz[r * (2 * DI) + DI + d];
      ybuf[r * DI + d] = (yp + Dv * xm) * silu_f(zv);
    }
  }
}

// ---------------- final (B,L,C) -> (B,C,H,W) transpose -----------------------
__global__ void __launch_bounds__(256) k_out_transpose(
    const float* __restrict__ yfin, float* __restrict__ out)
{
  int bc = blockIdx.x;               // b*CDM + c
  int b = bc >> 7; int c = bc & 127;
  for (int l = threadIdx.x; l < LL; l += 256)
    out[(size_t)bc * LL + l] = yfin[((size_t)(b << 12) + l) * CDM + c];
}

extern "C" void kernel_launch(void* const* d_in, const int* in_sizes, int n_in,
                              void* d_out, int out_size, void* d_ws, size_t ws_size,
                              hipStream_t stream) {
  const float* x          = (const float*)d_in[0];
  const float* norm1_g    = (const float*)d_in[1];
  const float* norm1_b    = (const float*)d_in[2];
  const float* in_proj_w  = (const float*)d_in[3];
  const float* dwconv_w   = (const float*)d_in[4];
  const float* m_in_w     = (const float*)d_in[5];
  const float* m_conv_w   = (const float*)d_in[6];
  const float* m_conv_b   = (const float*)d_in[7];
  const float* m_xproj_w  = (const float*)d_in[8];
  const float* m_dt_w     = (const float*)d_in[9];
  const float* m_dt_b     = (const float*)d_in[10];
  const float* m_A_log    = (const float*)d_in[11];
  const float* m_D        = (const float*)d_in[12];
  const float* m_out_w    = (const float*)d_in[13];
  const float* normss_g   = (const float*)d_in[14];
  const float* normss_b   = (const float*)d_in[15];
  const float* out_proj_w = (const float*)d_in[16];
  const float* norm2_g    = (const float*)d_in[17];
  const float* norm2_b    = (const float*)d_in[18];
  const float* ffn_w1     = (const float*)d_in[19];
  const float* ffn_w2     = (const float*)d_in[20];

  float* ws = (float*)d_ws;
  size_t o = 0;
  auto alloc = [&](size_t nf) { float* p = ws + o; o += nf; return p; };
  const size_t BL = (size_t)B_N * LL;       // 16384
  float* xflat = alloc(BL * CDM);  // raw (B,L,128)
  float* x1    = alloc(BL * CDM);  // LN1 out
  float* hbuf  = alloc(BL * DI);   // in_proj out; later reused as LN(y_comb)
  float* hc    = alloc(BL * DI);   // dwconv+silu out
  float* xz    = alloc(BL * 2 * DI); // per-dir xz (reused across dirs)
  float* xmc   = alloc(BL * DI);   // conv1d+silu out
  float* dt    = alloc(BL * DI);
  float* xbc   = alloc(BL * 8);
  float* ybuf  = alloc(BL * DI);   // scan out
  float* ycomb = alloc(BL * DI);   // 4-dir combined (pre /4 folded into 0.25)
  float* x2    = alloc(BL * CDM);
  float* x3    = alloc(BL * CDM);
  float* f1    = alloc(BL * CDM);
  float* yfin  = alloc(BL * CDM);
  // total ~44.1M floats = ~177 MB

  // 1. transpose + LN1
  k_ln1<<<B_N * LL, CDM, 0, stream>>>(x, norm1_g, norm1_b, xflat, x1);
  // 2. in_proj: (BL,128)@(256,128)^T -> h
  k_gemm<0><<<dim3(256, 4), 256, 0, stream>>>(x1, CDM, in_proj_w, hbuf, DI, CDM, 0, nullptr);
  // 3. dw 3x3 conv + silu
  k_dwconv<<<B_N * LL, DI, 0, stream>>>(hbuf, dwconv_w, hc);
  // 4. zero y_comb
  hipMemsetAsync(ycomb, 0, BL * DI * sizeof(float), stream);
  // 5. per-direction mamba
  for (int dir = 0; dir < 4; ++dir) {
    k_gemm<1><<<dim3(256, 8), 256, 0, stream>>>(
        hc, DI, m_in_w + (size_t)dir * 2 * DI * DI, xz, 2 * DI, DI, dir, nullptr);
    k_conv1d<<<B_N * LL, DI, 0, stream>>>(
        xz, m_conv_w + (size_t)dir * DI * DCV, m_conv_b + (size_t)dir * DI, xmc);
    k_xproj_dt<<<B_N * LL, 64, 0, stream>>>(
        xmc, m_xproj_w + (size_t)dir * 24 * DI, m_dt_w + (size_t)dir * DI * DTR,
        m_dt_b + (size_t)dir * DI, dt, xbc);
    k_scan<<<B_N * 16, 64, 0, stream>>>(
        dt, xmc, xbc, xz, m_A_log + (size_t)dir * DI * DS, m_D + (size_t)dir * DI, ybuf);
    k_gemm<2><<<dim3(256, 4), 256, 0, stream>>>(
        ybuf, DI, m_out_w + (size_t)dir * DI * DI, ycomb, DI, DI, dir, nullptr);
  }
  // 6. LN over 256 -> reuse hbuf
  k_ln<DI><<<B_N * LL, DI, 0, stream>>>(ycomb, normss_g, normss_b, hbuf);
  // 7. out_proj + residual(xflat) -> x2
  k_gemm<3><<<dim3(256, 2), 256, 0, stream>>>(hbuf, DI, out_proj_w, x2, CDM, DI, 0, xflat);
  // 8. LN2 -> x3
  k_ln<CDM><<<B_N * LL, CDM, 0, stream>>>(x2, norm2_g, norm2_b, x3);
  // 9. ffn1 + gelu -> f1
  k_gemm<4><<<dim3(256, 2), 256, 0, stream>>>(x3, CDM, ffn_w1, f1, CDM, CDM, 0, nullptr);
  // 10. ffn2 + residual(x2) -> yfin
  k_gemm<3><<<dim3(256, 2), 256, 0, stream>>>(f1, CDM, ffn_w2, yfin, CDM, CDM, 0, x2);
  // 11. (B,L,C) -> (B,C,H,W)
  k_out_transpose<<<B_N * CDM, 256, 0, stream>>>(yfin, (float*)d_out);
}

// Round 2
// 1046.393 us; speedup vs baseline: 9.8751x; 9.8751x over previous
//
#include <hip/hip_runtime.h>
#include <math.h>

// VSSBlock on MI355X — round 1: chunked parallel selective scan.
// Round-0 profile: k_scan (serial, 4096 threads) was 9.4ms of 10.3ms.
// Replace with 3-phase chunked linear recurrence (part / carry / fix).

#define B_N   4
#define CDM   128   // D_MODEL
#define HH    64
#define WW    64
#define LL    4096  // H*W
#define DI    256   // D_INNER
#define DS    4     // D_STATE
#define DCV   4     // D_CONV (1d causal)
#define DTR   16    // DT_RANK
#define CS    32    // scan chunk size
#define NC    (LL / CS)   // 128 chunks

__device__ __forceinline__ float silu_f(float x) { return x / (1.f + __expf(-x)); }
__device__ __forceinline__ float softplus_f(float x) {
  return (x > 20.f) ? x : log1pf(expf(x));
}
__device__ __forceinline__ float gelu_f(float x) {
  return 0.5f * x * (1.f + erff(x * 0.70710678118654752f));
}

// sequence position t of direction dir -> original flat index l (row-major h*W+w)
__device__ __forceinline__ int sigma_map(int dir, int t) {
  int tt = (dir & 1) ? (LL - 1 - t) : t;
  if (dir >= 2) tt = ((tt & 63) << 6) | (tt >> 6);  // H=W=64 transpose
  return tt;
}

// ---------------- LN over C=128 with NCHW->(B,L,C) transpose, keeps raw copy ----
__global__ void __launch_bounds__(128) k_ln1(
    const float* __restrict__ x, const float* __restrict__ g,
    const float* __restrict__ be, float* __restrict__ xflat,
    float* __restrict__ x1)
{
  int row = blockIdx.x;                 // b*L + l
  int b = row >> 12; int l = row & (LL - 1);
  int c = threadIdx.x;
  float v = x[((size_t)b * CDM + c) * LL + l];
  __shared__ float red[CDM];
  red[c] = v; __syncthreads();
  #pragma unroll
  for (int s = CDM / 2; s > 0; s >>= 1) { if (c < s) red[c] += red[c + s]; __syncthreads(); }
  float mean = red[0] * (1.f / CDM);
  __syncthreads();
  float dv = v - mean;
  red[c] = dv * dv; __syncthreads();
  #pragma unroll
  for (int s = CDM / 2; s > 0; s >>= 1) { if (c < s) red[c] += red[c + s]; __syncthreads(); }
  float var = red[0] * (1.f / CDM);
  size_t o = (size_t)row * CDM + c;
  xflat[o] = v;
  x1[o] = dv * rsqrtf(var + 1e-5f) * g[c] + be[c];
}

// ---------------- generic row LayerNorm, WIDTH = block size ----------------
template<int WIDTH>
__global__ void __launch_bounds__(WIDTH) k_ln(
    const float* __restrict__ in, const float* __restrict__ g,
    const float* __restrict__ be, float* __restrict__ out)
{
  int row = blockIdx.x;
  int c = threadIdx.x;
  float v = in[(size_t)row * WIDTH + c];
  __shared__ float red[WIDTH];
  red[c] = v; __syncthreads();
  #pragma unroll
  for (int s = WIDTH / 2; s > 0; s >>= 1) { if (c < s) red[c] += red[c + s]; __syncthreads(); }
  float mean = red[0] * (1.f / WIDTH);
  __syncthreads();
  float dv = v - mean;
  red[c] = dv * dv; __syncthreads();
  #pragma unroll
  for (int s = WIDTH / 2; s > 0; s >>= 1) { if (c < s) red[c] += red[c + s]; __syncthreads(); }
  float var = red[0] * (1.f / WIDTH);
  out[(size_t)row * WIDTH + c] = dv * rsqrtf(var + 1e-5f) * g[c] + be[c];
}

// ---------------- generic SGEMM: C(M,N) = A(M,K) @ Wt(N,K)^T ----------------
// 64x64 tile, K-step 16, 256 threads, 4x4 per thread.
// MODE 0: plain store.  MODE 1: A-rows gathered via sigma_map(dir,t).
// MODE 2: scatter C[sigma row] += 0.25*acc.  MODE 3: C = resid + acc.
// MODE 4: C = gelu(acc).
template<int MODE>
__global__ void __launch_bounds__(256) k_gemm(
    const float* __restrict__ A, int lda,
    const float* __restrict__ Wt,
    float* __restrict__ C, int ldc, int K,
    int dir, const float* __restrict__ resid)
{
  __shared__ float As[16][65];
  __shared__ float Ws[16][65];
  int tid = threadIdx.x;
  int m0 = blockIdx.x << 6, n0 = blockIdx.y << 6;
  int li = tid >> 2;            // 0..63 tile row
  int lk = (tid & 3) << 2;      // 0,4,8,12
  int tx = tid & 15, ty = tid >> 4;
  float acc[4][4] = {};
  int arow = m0 + li;
  if (MODE == 1) { int b = arow >> 12; int t = arow & (LL - 1); arow = (b << 12) + sigma_map(dir, t); }
  const float* ap = A + (size_t)arow * lda + lk;
  const float* wp = Wt + (size_t)(n0 + li) * K + lk;
  for (int k0 = 0; k0 < K; k0 += 16) {
    float4 av = *(const float4*)(ap + k0);
    float4 wv = *(const float4*)(wp + k0);
    As[lk + 0][li] = av.x; As[lk + 1][li] = av.y; As[lk + 2][li] = av.z; As[lk + 3][li] = av.w;
    Ws[lk + 0][li] = wv.x; Ws[lk + 1][li] = wv.y; Ws[lk + 2][li] = wv.z; Ws[lk + 3][li] = wv.w;
    __syncthreads();
    #pragma unroll
    for (int kk = 0; kk < 16; ++kk) {
      float a0 = As[kk][(ty << 2) + 0], a1 = As[kk][(ty << 2) + 1];
      float a2 = As[kk][(ty << 2) + 2], a3 = As[kk][(ty << 2) + 3];
      float b0 = Ws[kk][(tx << 2) + 0], b1 = Ws[kk][(tx << 2) + 1];
      float b2 = Ws[kk][(tx << 2) + 2], b3 = Ws[kk][(tx << 2) + 3];
      acc[0][0] += a0 * b0; acc[0][1] += a0 * b1; acc[0][2] += a0 * b2; acc[0][3] += a0 * b3;
      acc[1][0] += a1 * b0; acc[1][1] += a1 * b1; acc[1][2] += a1 * b2; acc[1][3] += a1 * b3;
      acc[2][0] += a2 * b0; acc[2][1] += a2 * b1; acc[2][2] += a2 * b2; acc[2][3] += a2 * b3;
      acc[3][0] += a3 * b0; acc[3][1] += a3 * b1; acc[3][2] += a3 * b2; acc[3][3] += a3 * b3;
    }
    __syncthreads();
  }
  #pragma unroll
  for (int r = 0; r < 4; ++r) {
    int row = m0 + (ty << 2) + r;
    int orow = row;
    if (MODE == 2) { int b = row >> 12; int t = row & (LL - 1); orow = (b << 12) + sigma_map(dir, t); }
    #pragma unroll
    for (int q = 0; q < 4; ++q) {
      int col = n0 + (tx << 2) + q;
      size_t off = (size_t)orow * ldc + col;
      float v = acc[r][q];
      if (MODE == 2)      C[off] += 0.25f * v;
      else if (MODE == 3) C[off] = resid[off] + v;
      else if (MODE == 4) C[off] = gelu_f(v);
      else                C[off] = v;
    }
  }
}

// ---------------- depthwise 3x3 conv (NHWC, same pad) + SiLU ----------------
__global__ void __launch_bounds__(256) k_dwconv(
    const float* __restrict__ h, const float* __restrict__ wgt,
    float* __restrict__ out)
{
  int p = blockIdx.x;                 // b*L + l
  int b = p >> 12; int l = p & (LL - 1);
  int hy = l >> 6, wx = l & 63;
  int d = threadIdx.x;
  float acc = 0.f;
  #pragma unroll
  for (int di = -1; di <= 1; ++di) {
    int yy = hy + di; if (yy < 0 || yy >= HH) continue;
    #pragma unroll
    for (int dj = -1; dj <= 1; ++dj) {
      int xx = wx + dj; if (xx < 0 || xx >= WW) continue;
      acc += wgt[d * 9 + (di + 1) * 3 + (dj + 1)] *
             h[(((size_t)b << 12) + (yy << 6) + xx) * DI + d];
    }
  }
  out[(size_t)p * DI + d] = silu_f(acc);
}

// ---------------- causal depthwise conv1d (k=4) + SiLU, reads xm slice of xz ----
__global__ void __launch_bounds__(256) k_conv1d(
    const float* __restrict__ xz, const float* __restrict__ cw,
    const float* __restrict__ cb, float* __restrict__ xmc)
{
  int p = blockIdx.x;                 // b*L + t
  int b = p >> 12; int t = p & (LL - 1);
  int d = threadIdx.x;
  float acc = cb[d];
  #pragma unroll
  for (int k = 0; k < DCV; ++k) {
    int tt = t - (DCV - 1) + k;
    if (tt >= 0)
      acc += cw[d * DCV + k] * xz[((size_t)(b << 12) + tt) * (2 * DI) + d];
  }
  xmc[(size_t)p * DI + d] = silu_f(acc);
}

// ---------------- fused x_proj (24 outputs) + dt projection + softplus --------
__global__ void __launch_bounds__(64) k_xproj_dt(
    const float* __restrict__ xmc,
    const float* __restrict__ xw,    // (24,256) this dir
    const float* __restrict__ dtw,   // (256,16) this dir
    const float* __restrict__ dtb,   // (256)    this dir
    float* __restrict__ dtout,
    float* __restrict__ xbc)
{
  int m = blockIdx.x;
  int lane = threadIdx.x;            // 0..63
  float4 xv = *(const float4*)(xmc + (size_t)m * DI + lane * 4);
  float sbuf[24];
  #pragma unroll
  for (int n = 0; n < 24; ++n) {
    float4 wv = *(const float4*)(xw + n * DI + lane * 4);
    float p = xv.x * wv.x + xv.y * wv.y + xv.z * wv.z + xv.w * wv.w;
    #pragma unroll
    for (int o = 1; o < 64; o <<= 1) p += __shfl_xor(p, o);
    sbuf[n] = p;
  }
  #pragma unroll
  for (int n = 16; n < 24; ++n)
    if (lane == n - 16) xbc[(size_t)m * 8 + (n - 16)] = sbuf[n];
  #pragma unroll
  for (int j = 0; j < 4; ++j) {
    int np = j * 64 + lane;
    float acc = dtb[np];
    const float* dw = dtw + np * DTR;
    #pragma unroll
    for (int k = 0; k < DTR; ++k) acc += sbuf[k] * dw[k];
    dtout[(size_t)m * DI + np] = softplus_f(acc);
  }
}

// ================= chunked selective scan =====================================
// Phase 1: per (b,chunk): local scan from h=0. One thread per d (256/block),
// DS=4 states in registers. Emits P = prod(dA) and H = local final state.
__global__ void __launch_bounds__(256) k_scan_part(
    const float* __restrict__ dtbuf, const float* __restrict__ xmc,
    const float* __restrict__ xbc, const float* __restrict__ Alog,
    float* __restrict__ Pbuf, float* __restrict__ Hbuf)
{
  int blk = blockIdx.x;                 // b*NC + ch
  int b = blk >> 7; int ch = blk & (NC - 1);
  int d = threadIdx.x;
  float Av[DS], h[DS], P[DS];
  #pragma unroll
  for (int n = 0; n < DS; ++n) { Av[n] = -expf(Alog[d * DS + n]); h[n] = 0.f; P[n] = 1.f; }
  size_t base = (size_t)b * LL + (size_t)ch * CS;
  #pragma unroll 4
  for (int t = 0; t < CS; ++t) {
    size_t r = base + t;
    float dt = dtbuf[r * DI + d];
    float xm = xmc[r * DI + d];
    float4 Bv = *(const float4*)(xbc + r * 8);
    float bx = dt * xm;
    float dA0 = __expf(dt * Av[0]), dA1 = __expf(dt * Av[1]);
    float dA2 = __expf(dt * Av[2]), dA3 = __expf(dt * Av[3]);
    h[0] = dA0 * h[0] + bx * Bv.x; P[0] *= dA0;
    h[1] = dA1 * h[1] + bx * Bv.y; P[1] *= dA1;
    h[2] = dA2 * h[2] + bx * Bv.z; P[2] *= dA2;
    h[3] = dA3 * h[3] + bx * Bv.w; P[3] *= dA3;
  }
  size_t o = ((size_t)blk * DI + d) * DS;
  #pragma unroll
  for (int n = 0; n < DS; ++n) { Pbuf[o + n] = P[n]; Hbuf[o + n] = h[n]; }
}

// Phase 2: sequential combine over chunks, per (b,d,n). Rewrites Hbuf in place
// with the ENTRY state of each chunk (carry before the chunk).
__global__ void __launch_bounds__(256) k_scan_carry(
    const float* __restrict__ Pbuf, float* __restrict__ Hbuf)
{
  int idx = blockIdx.x * 256 + threadIdx.x;   // 0 .. B*DI*DS-1  (4096)
  int b = idx >> 10; int dn = idx & 1023;
  float carry = 0.f;
  #pragma unroll 8
  for (int ch = 0; ch < NC; ++ch) {
    size_t o = (((size_t)b * NC + ch) * DI * DS) + dn;
    float Pv = Pbuf[o], Hv = Hbuf[o];
    Hbuf[o] = carry;
    carry = Pv * carry + Hv;
  }
}

// Phase 3: re-run each chunk from its entry state; produce gated output.
__global__ void __launch_bounds__(256) k_scan_fix(
    const float* __restrict__ dtbuf, const float* __restrict__ xmc,
    const float* __restrict__ xbc, const float* __restrict__ xz,
    const float* __restrict__ Alog, const float* __restrict__ Dp,
    const float* __restrict__ Cin,   // = Hbuf (entry states)
    float* __restrict__ ybuf)
{
  int blk = blockIdx.x;
  int b = blk >> 7; int ch = blk & (NC - 1);
  int d = threadIdx.x;
  float Av[DS], h[DS];
  size_t ci = ((size_t)blk * DI + d) * DS;
  #pragma unroll
  for (int n = 0; n < DS; ++n) { Av[n] = -expf(Alog[d * DS + n]); h[n] = Cin[ci + n]; }
  float Dv = Dp[d];
  size_t base = (size_t)b * LL + (size_t)ch * CS;
  #pragma unroll 4
  for (int t = 0; t < CS; ++t) {
    size_t r = base + t;
    float dt = dtbuf[r * DI + d];
    float xm = xmc[r * DI + d];
    float4 Bv = *(const float4*)(xbc + r * 8);
    float4 Cv = *(const float4*)(xbc + r * 8 + 4);
    float bx = dt * xm;
    float dA0 = __expf(dt * Av[0]), dA1 = __expf(dt * Av[1]);
    float dA2 = __expf(dt * Av[2]), dA3 = __expf(dt * Av[3]);
    h[0] = dA0 * h[0] + bx * Bv.x;
    h[1] = dA1 * h[1] + bx * Bv.y;
    h[2] = dA2 * h[2] + bx * Bv.z;
    h[3] = dA3 * h[3] + bx * Bv.w;
    float y = h[0] * Cv.x + h[1] * Cv.y + h[2] * Cv.z + h[3] * Cv.w;
    float zv = xz[r * (2 * DI) + DI + d];
    ybuf[r * DI + d] = (y + Dv * xm) * silu_f(zv);
  }
}

// ---------------- final (B,L,C) -> (B,C,H,W) transpose -----------------------
__global__ void __launch_bounds__(256) k_out_transpose(
    const float* __restrict__ yfin, float* __restrict__ out)
{
  int bc = blockIdx.x;               // b*CDM + c
  int b = bc >> 7; int c = bc & 127;
  for (int l = threadIdx.x; l < LL; l += 256)
    out[(size_t)bc * LL + l] = yfin[((size_t)(b << 12) + l) * CDM + c];
}

extern "C" void kernel_launch(void* const* d_in, const int* in_sizes, int n_in,
                              void* d_out, int out_size, void* d_ws, size_t ws_size,
                              hipStream_t stream) {
  const float* x          = (const float*)d_in[0];
  const float* norm1_g    = (const float*)d_in[1];
  const float* norm1_b    = (const float*)d_in[2];
  const float* in_proj_w  = (const float*)d_in[3];
  const float* dwconv_w   = (const float*)d_in[4];
  const float* m_in_w     = (const float*)d_in[5];
  const float* m_conv_w   = (const float*)d_in[6];
  const float* m_conv_b   = (const float*)d_in[7];
  const float* m_xproj_w  = (const float*)d_in[8];
  const float* m_dt_w     = (const float*)d_in[9];
  const float* m_dt_b     = (const float*)d_in[10];
  const float* m_A_log    = (const float*)d_in[11];
  const float* m_D        = (const float*)d_in[12];
  const float* m_out_w    = (const float*)d_in[13];
  const float* normss_g   = (const float*)d_in[14];
  const float* normss_b   = (const float*)d_in[15];
  const float* out_proj_w = (const float*)d_in[16];
  const float* norm2_g    = (const float*)d_in[17];
  const float* norm2_b    = (const float*)d_in[18];
  const float* ffn_w1     = (const float*)d_in[19];
  const float* ffn_w2     = (const float*)d_in[20];

  float* ws = (float*)d_ws;
  size_t o = 0;
  auto alloc = [&](size_t nf) { float* p = ws + o; o += nf; return p; };
  const size_t BL = (size_t)B_N * LL;       // 16384
  float* xflat = alloc(BL * CDM);
  float* x1    = alloc(BL * CDM);
  float* hbuf  = alloc(BL * DI);
  float* hc    = alloc(BL * DI);
  float* xz    = alloc(BL * 2 * DI);
  float* xmc   = alloc(BL * DI);
  float* dt    = alloc(BL * DI);
  float* xbc   = alloc(BL * 8);
  float* ybuf  = alloc(BL * DI);
  float* ycomb = alloc(BL * DI);
  float* x2    = alloc(BL * CDM);
  float* x3    = alloc(BL * CDM);
  float* f1    = alloc(BL * CDM);
  float* yfin  = alloc(BL * CDM);
  float* Pbuf  = alloc((size_t)B_N * NC * DI * DS);  // 524288 floats
  float* Hbuf  = alloc((size_t)B_N * NC * DI * DS);

  // 1. transpose + LN1
  k_ln1<<<B_N * LL, CDM, 0, stream>>>(x, norm1_g, norm1_b, xflat, x1);
  // 2. in_proj
  k_gemm<0><<<dim3(256, 4), 256, 0, stream>>>(x1, CDM, in_proj_w, hbuf, DI, CDM, 0, nullptr);
  // 3. dw 3x3 conv + silu
  k_dwconv<<<B_N * LL, DI, 0, stream>>>(hbuf, dwconv_w, hc);
  // 4. zero y_comb
  hipMemsetAsync(ycomb, 0, BL * DI * sizeof(float), stream);
  // 5. per-direction mamba
  for (int dir = 0; dir < 4; ++dir) {
    k_gemm<1><<<dim3(256, 8), 256, 0, stream>>>(
        hc, DI, m_in_w + (size_t)dir * 2 * DI * DI, xz, 2 * DI, DI, dir, nullptr);
    k_conv1d<<<B_N * LL, DI, 0, stream>>>(
        xz, m_conv_w + (size_t)dir * DI * DCV, m_conv_b + (size_t)dir * DI, xmc);
    k_xproj_dt<<<B_N * LL, 64, 0, stream>>>(
        xmc, m_xproj_w + (size_t)dir * 24 * DI, m_dt_w + (size_t)dir * DI * DTR,
        m_dt_b + (size_t)dir * DI, dt, xbc);
    const float* Alog_d = m_A_log + (size_t)dir * DI * DS;
    k_scan_part<<<B_N * NC, 256, 0, stream>>>(dt, xmc, xbc, Alog_d, Pbuf, Hbuf);
    k_scan_carry<<<16, 256, 0, stream>>>(Pbuf, Hbuf);
    k_scan_fix<<<B_N * NC, 256, 0, stream>>>(
        dt, xmc, xbc, xz, Alog_d, m_D + (size_t)dir * DI, Hbuf, ybuf);
    k_gemm<2><<<dim3(256, 4), 256, 0, stream>>>(
        ybuf, DI, m_out_w + (size_t)dir * DI * DI, ycomb, DI, DI, dir, nullptr);
  }
  // 6. LN over 256
  k_ln<DI><<<B_N * LL, DI, 0, stream>>>(ycomb, normss_g, normss_b, hbuf);
  // 7. out_proj + residual
  k_gemm<3><<<dim3(256, 2), 256, 0, stream>>>(hbuf, DI, out_proj_w, x2, CDM, DI, 0, xflat);
  // 8. LN2
  k_ln<CDM><<<B_N * LL, CDM, 0, stream>>>(x2, norm2_g, norm2_b, x3);
  // 9. ffn1 + gelu
  k_gemm<4><<<dim3(256, 2), 256, 0, stream>>>(x3, CDM, ffn_w1, f1, CDM, CDM, 0, nullptr);
  // 10. ffn2 + residual
  k_gemm<3><<<dim3(256, 2), 256, 0, stream>>>(f1, CDM, ffn_w2, yfin, CDM, CDM, 0, x2);
  // 11. transpose out
  k_out_transpose<<<B_N * CDM, 256, 0, stream>>>(yfin, (float*)d_out);
}

// Round 3
// 605.646 us; speedup vs baseline: 17.0614x; 1.7277x over previous
//
#include <hip/hip_runtime.h>
#include <math.h>

// VSSBlock on MI355X — round 2: all GEMMs -> bf16 MFMA (16x16x32), m97-style
// 128x128 tile, BK=64, global_load_lds(16). fp32 k_gemm removed.

#define B_N   4
#define CDM   128
#define HH    64
#define WW    64
#define LL    4096
#define DI    256
#define DS    4
#define DCV   4
#define DTR   16
#define CS    32
#define NC    (LL / CS)

typedef float    f32x4  __attribute__((ext_vector_type(4)));
typedef __bf16   bf16x8 __attribute__((ext_vector_type(8)));

__device__ __forceinline__ float silu_f(float x) { return x / (1.f + __expf(-x)); }
__device__ __forceinline__ float softplus_f(float x) {
  return (x > 20.f) ? x : log1pf(expf(x));
}
__device__ __forceinline__ float gelu_f(float x) {
  return 0.5f * x * (1.f + erff(x * 0.70710678118654752f));
}
__device__ __forceinline__ ushort f2bf(float x) {
  unsigned u = __builtin_bit_cast(unsigned, x);
  u += 0x7fffu + ((u >> 16) & 1u);          // RNE
  return (ushort)(u >> 16);
}
__device__ __forceinline__ float bf2f(ushort u) {
  return __builtin_bit_cast(float, (unsigned)u << 16);
}

// sequence position t of direction dir -> original flat index l
__device__ __forceinline__ int sigma_map(int dir, int t) {
  int tt = (dir & 1) ? (LL - 1 - t) : t;
  if (dir >= 2) tt = ((tt & 63) << 6) | (tt >> 6);
  return tt;
}

// ---------------- weight fp32 -> bf16 conversion (one pass, 8 segments) -------
__global__ void __launch_bounds__(256) k_cvt(
    const float* __restrict__ s0, const float* __restrict__ s1,
    const float* __restrict__ s2, const float* __restrict__ s3,
    const float* __restrict__ s4, const float* __restrict__ s5,
    const float* __restrict__ s6, const float* __restrict__ s7,
    ushort* __restrict__ dst)
{
  int i = (blockIdx.x * 256 + threadIdx.x) * 4;   // element index (x4)
  const float* s; int base;
  if      (i < 32768)  { s = s0; base = 0; }
  else if (i < 557056) { s = s1; base = 32768; }
  else if (i < 819200) { s = s2; base = 557056; }
  else if (i < 851968) { s = s3; base = 819200; }
  else if (i < 868352) { s = s4; base = 851968; }
  else if (i < 884736) { s = s5; base = 868352; }
  else if (i < 909312) { s = s6; base = 884736; }
  else if (i < 925696) { s = s7; base = 909312; }
  else return;
  float4 v = *(const float4*)(s + (i - base));
  dst[i+0] = f2bf(v.x); dst[i+1] = f2bf(v.y); dst[i+2] = f2bf(v.z); dst[i+3] = f2bf(v.w);
}

// ---------------- LN1 with NCHW->(B,L,C) transpose; bf16 + raw f32 out --------
__global__ void __launch_bounds__(128) k_ln1(
    const float* __restrict__ x, const float* __restrict__ g,
    const float* __restrict__ be, float* __restrict__ xflat,
    ushort* __restrict__ x1b)
{
  int row = blockIdx.x;
  int b = row >> 12; int l = row & (LL - 1);
  int c = threadIdx.x;
  float v = x[((size_t)b * CDM + c) * LL + l];
  __shared__ float red[CDM];
  red[c] = v; __syncthreads();
  #pragma unroll
  for (int s = CDM / 2; s > 0; s >>= 1) { if (c < s) red[c] += red[c + s]; __syncthreads(); }
  float mean = red[0] * (1.f / CDM);
  __syncthreads();
  float dv = v - mean;
  red[c] = dv * dv; __syncthreads();
  #pragma unroll
  for (int s = CDM / 2; s > 0; s >>= 1) { if (c < s) red[c] += red[c + s]; __syncthreads(); }
  float var = red[0] * (1.f / CDM);
  size_t o = (size_t)row * CDM + c;
  xflat[o] = v;
  x1b[o] = f2bf(dv * rsqrtf(var + 1e-5f) * g[c] + be[c]);
}

// ---------------- row LayerNorm -> bf16 out ----------------------------------
template<int WIDTH>
__global__ void __launch_bounds__(WIDTH) k_ln(
    const float* __restrict__ in, const float* __restrict__ g,
    const float* __restrict__ be, ushort* __restrict__ out)
{
  int row = blockIdx.x;
  int c = threadIdx.x;
  float v = in[(size_t)row * WIDTH + c];
  __shared__ float red[WIDTH];
  red[c] = v; __syncthreads();
  #pragma unroll
  for (int s = WIDTH / 2; s > 0; s >>= 1) { if (c < s) red[c] += red[c + s]; __syncthreads(); }
  float mean = red[0] * (1.f / WIDTH);
  __syncthreads();
  float dv = v - mean;
  red[c] = dv * dv; __syncthreads();
  #pragma unroll
  for (int s = WIDTH / 2; s > 0; s >>= 1) { if (c < s) red[c] += red[c + s]; __syncthreads(); }
  float var = red[0] * (1.f / WIDTH);
  out[(size_t)row * WIDTH + c] = f2bf(dv * rsqrtf(var + 1e-5f) * g[c] + be[c]);
}

// ---------------- bf16 MFMA GEMM: C(M,N) = A(M,K) @ Wt(N,K)^T -----------------
// 128x128 tile, BK=64, 256 thr = 4 waves (2x2 of 64x64), 4x4 16x16 frags/wave.
// GATHER=1: A rows gathered via sigma_map(dir,t) in the global_load_lds source.
// EPI: 0 = f32 store, 2 = f32 scatter C[sigma]+=0.25v, 3 = f32 resid+v,
//      4 = bf16 gelu(v).
template<int GATHER, int EPI>
__global__ void __launch_bounds__(256) k_mgemm(
    const ushort* __restrict__ A, int lda,
    const ushort* __restrict__ Wt,
    float* __restrict__ Cf, ushort* __restrict__ Cb,
    int ldc, int K, int dir, const float* __restrict__ resid)
{
  __shared__ ushort As[128 * 64];
  __shared__ ushort Ws[128 * 64];
  int tid = threadIdx.x;
  int m0 = blockIdx.x << 7, n0 = blockIdx.y << 7;
  int lane = tid & 63;
  int wm = ((tid >> 7) & 1) * 64;        // wave row (waves 0,1 / 2,3)
  int wn = ((tid >> 6) & 1) * 64;        // wave col
  int r15 = lane & 15, khi = lane >> 4;

  // staging geometry: linear slot s = i*256 + tid -> row s/8, col (s%8)*8
  int srow = tid >> 3;
  int scol = (tid & 7) << 3;
  int arow[4];
  #pragma unroll
  for (int i = 0; i < 4; ++i) {
    int r = m0 + i * 32 + srow;
    if (GATHER) { int b = r >> 12; int t = r & (LL - 1); r = (b << 12) + sigma_map(dir, t); }
    arow[i] = r;
  }
  int wrow[4];
  #pragma unroll
  for (int i = 0; i < 4; ++i) wrow[i] = n0 + i * 32 + srow;

  f32x4 acc[4][4] = {};
  int wavebase = (tid & 192) * 8;        // ushort index of this wave's 1KB slot

  for (int ks = 0; ks < K; ks += 64) {
    if (ks) __syncthreads();
    #pragma unroll
    for (int i = 0; i < 4; ++i) {
      const ushort* gA = A + (size_t)arow[i] * lda + ks + scol;
      __builtin_amdgcn_global_load_lds(
          (const __attribute__((address_space(1))) void*)gA,
          (__attribute__((address_space(3))) void*)(As + i * 2048 + wavebase),
          16, 0, 0);
    }
    #pragma unroll
    for (int i = 0; i < 4; ++i) {
      const ushort* gW = Wt + (size_t)wrow[i] * K + ks + scol;
      __builtin_amdgcn_global_load_lds(
          (const __attribute__((address_space(1))) void*)gW,
          (__attribute__((address_space(3))) void*)(Ws + i * 2048 + wavebase),
          16, 0, 0);
    }
    __syncthreads();   // compiler drains vmcnt before s_barrier
    #pragma unroll
    for (int kk = 0; kk < 2; ++kk) {
      bf16x8 af[4], wf[4];
      #pragma unroll
      for (int mi = 0; mi < 4; ++mi)
        af[mi] = *(const bf16x8*)&As[(wm + mi * 16 + r15) * 64 + kk * 32 + khi * 8];
      #pragma unroll
      for (int ni = 0; ni < 4; ++ni)
        wf[ni] = *(const bf16x8*)&Ws[(wn + ni * 16 + r15) * 64 + kk * 32 + khi * 8];
      #pragma unroll
      for (int mi = 0; mi < 4; ++mi)
        #pragma unroll
        for (int ni = 0; ni < 4; ++ni)
          acc[mi][ni] = __builtin_amdgcn_mfma_f32_16x16x32_bf16(
              af[mi], wf[ni], acc[mi][ni], 0, 0, 0);
    }
  }

  #pragma unroll
  for (int mi = 0; mi < 4; ++mi) {
    #pragma unroll
    for (int j = 0; j < 4; ++j) {
      int row = m0 + wm + mi * 16 + khi * 4 + j;
      int orow = row;
      if (EPI == 2) { int b = row >> 12; int t = row & (LL - 1); orow = (b << 12) + sigma_map(dir, t); }
      #pragma unroll
      for (int ni = 0; ni < 4; ++ni) {
        int col = n0 + wn + ni * 16 + r15;
        size_t off = (size_t)orow * ldc + col;
        float v = acc[mi][ni][j];
        if      (EPI == 0) Cf[off] = v;
        else if (EPI == 2) Cf[off] += 0.25f * v;
        else if (EPI == 3) Cf[off] = resid[off] + v;
        else if (EPI == 4) Cb[off] = f2bf(gelu_f(v));
      }
    }
  }
}

// ---------------- depthwise 3x3 conv (NHWC, same pad) + SiLU -> bf16 ----------
__global__ void __launch_bounds__(256) k_dwconv(
    const float* __restrict__ h, const float* __restrict__ wgt,
    ushort* __restrict__ out)
{
  int p = blockIdx.x;
  int b = p >> 12; int l = p & (LL - 1);
  int hy = l >> 6, wx = l & 63;
  int d = threadIdx.x;
  float acc = 0.f;
  #pragma unroll
  for (int di = -1; di <= 1; ++di) {
    int yy = hy + di; if (yy < 0 || yy >= HH) continue;
    #pragma unroll
    for (int dj = -1; dj <= 1; ++dj) {
      int xx = wx + dj; if (xx < 0 || xx >= WW) continue;
      acc += wgt[d * 9 + (di + 1) * 3 + (dj + 1)] *
             h[(((size_t)b << 12) + (yy << 6) + xx) * DI + d];
    }
  }
  out[(size_t)p * DI + d] = f2bf(silu_f(acc));
}

// ---------------- causal depthwise conv1d (k=4) + SiLU ------------------------
__global__ void __launch_bounds__(256) k_conv1d(
    const float* __restrict__ xz, const float* __restrict__ cw,
    const float* __restrict__ cb, float* __restrict__ xmc)
{
  int p = blockIdx.x;
  int b = p >> 12; int t = p & (LL - 1);
  int d = threadIdx.x;
  float acc = cb[d];
  #pragma unroll
  for (int k = 0; k < DCV; ++k) {
    int tt = t - (DCV - 1) + k;
    if (tt >= 0)
      acc += cw[d * DCV + k] * xz[((size_t)(b << 12) + tt) * (2 * DI) + d];
  }
  xmc[(size_t)p * DI + d] = silu_f(acc);
}

// ---------------- fused x_proj + dt projection + softplus ---------------------
// 256 threads = 4 waves, 4 rows per block; bf16 weights (L1-resident).
__global__ void __launch_bounds__(256) k_xproj_dt(
    const float* __restrict__ xmc,
    const ushort* __restrict__ xw,    // (24,256) bf16
    const ushort* __restrict__ dtw,   // (256,16) bf16
    const float* __restrict__ dtb,
    float* __restrict__ dtout, float* __restrict__ xbc)
{
  int m = (blockIdx.x << 2) + (threadIdx.x >> 6);
  int lane = threadIdx.x & 63;
  float4 xv = *(const float4*)(xmc + (size_t)m * DI + (lane << 2));
  float sbuf[24];
  #pragma unroll
  for (int n = 0; n < 24; ++n) {
    ushort4 wv = *(const ushort4*)(xw + n * DI + (lane << 2));
    float p = xv.x * bf2f(wv.x) + xv.y * bf2f(wv.y) + xv.z * bf2f(wv.z) + xv.w * bf2f(wv.w);
    #pragma unroll
    for (int o = 1; o < 64; o <<= 1) p += __shfl_xor(p, o);
    sbuf[n] = p;
  }
  if (lane < 8) xbc[(size_t)m * 8 + lane] = sbuf[16 + lane];
  #pragma unroll
  for (int j = 0; j < 4; ++j) {
    int np = (j << 6) + lane;
    float acc = dtb[np];
    #pragma unroll
    for (int k = 0; k < DTR; ++k) acc += sbuf[k] * bf2f(dtw[np * DTR + k]);
    dtout[(size_t)m * DI + np] = softplus_f(acc);
  }
}

// ================= chunked selective scan =====================================
__global__ void __launch_bounds__(256) k_scan_part(
    const float* __restrict__ dtbuf, const float* __restrict__ xmc,
    const float* __restrict__ xbc, const float* __restrict__ Alog,
    float* __restrict__ Pbuf, float* __restrict__ Hbuf)
{
  int blk = blockIdx.x;
  int b = blk >> 7; int ch = blk & (NC - 1);
  int d = threadIdx.x;
  float Av[DS], h[DS], P[DS];
  #pragma unroll
  for (int n = 0; n < DS; ++n) { Av[n] = -expf(Alog[d * DS + n]); h[n] = 0.f; P[n] = 1.f; }
  size_t base = (size_t)b * LL + (size_t)ch * CS;
  #pragma unroll 4
  for (int t = 0; t < CS; ++t) {
    size_t r = base + t;
    float dt = dtbuf[r * DI + d];
    float xm = xmc[r * DI + d];
    float4 Bv = *(const float4*)(xbc + r * 8);
    float bx = dt * xm;
    float dA0 = __expf(dt * Av[0]), dA1 = __expf(dt * Av[1]);
    float dA2 = __expf(dt * Av[2]), dA3 = __expf(dt * Av[3]);
    h[0] = dA0 * h[0] + bx * Bv.x; P[0] *= dA0;
    h[1] = dA1 * h[1] + bx * Bv.y; P[1] *= dA1;
    h[2] = dA2 * h[2] + bx * Bv.z; P[2] *= dA2;
    h[3] = dA3 * h[3] + bx * Bv.w; P[3] *= dA3;
  }
  size_t o = ((size_t)blk * DI + d) * DS;
  #pragma unroll
  for (int n = 0; n < DS; ++n) { Pbuf[o + n] = P[n]; Hbuf[o + n] = h[n]; }
}

__global__ void __launch_bounds__(256) k_scan_carry(
    const float* __restrict__ Pbuf, float* __restrict__ Hbuf)
{
  int idx = blockIdx.x * 256 + threadIdx.x;
  int b = idx >> 10; int dn = idx & 1023;
  float carry = 0.f;
  #pragma unroll 8
  for (int ch = 0; ch < NC; ++ch) {
    size_t o = (((size_t)b * NC + ch) * DI * DS) + dn;
    float Pv = Pbuf[o], Hv = Hbuf[o];
    Hbuf[o] = carry;
    carry = Pv * carry + Hv;
  }
}

__global__ void __launch_bounds__(256) k_scan_fix(
    const float* __restrict__ dtbuf, const float* __restrict__ xmc,
    const float* __restrict__ xbc, const float* __restrict__ xz,
    const float* __restrict__ Alog, const float* __restrict__ Dp,
    const float* __restrict__ Cin, ushort* __restrict__ ybuf)
{
  int blk = blockIdx.x;
  int b = blk >> 7; int ch = blk & (NC - 1);
  int d = threadIdx.x;
  float Av[DS], h[DS];
  size_t ci = ((size_t)blk * DI + d) * DS;
  #pragma unroll
  for (int n = 0; n < DS; ++n) { Av[n] = -expf(Alog[d * DS + n]); h[n] = Cin[ci + n]; }
  float Dv = Dp[d];
  size_t base = (size_t)b * LL + (size_t)ch * CS;
  #pragma unroll 4
  for (int t = 0; t < CS; ++t) {
    size_t r = base + t;
    float dt = dtbuf[r * DI + d];
    float xm = xmc[r * DI + d];
    float4 Bv = *(const float4*)(xbc + r * 8);
    float4 Cv = *(const float4*)(xbc + r * 8 + 4);
    float bx = dt * xm;
    float dA0 = __expf(dt * Av[0]), dA1 = __expf(dt * Av[1]);
    float dA2 = __expf(dt * Av[2]), dA3 = __expf(dt * Av[3]);
    h[0] = dA0 * h[0] + bx * Bv.x;
    h[1] = dA1 * h[1] + bx * Bv.y;
    h[2] = dA2 * h[2] + bx * Bv.z;
    h[3] = dA3 * h[3] + bx * Bv.w;
    float y = h[0] * Cv.x + h[1] * Cv.y + h[2] * Cv.z + h[3] * Cv.w;
    float zv = xz[r * (2 * DI) + DI + d];
    ybuf[r * DI + d] = f2bf((y + Dv * xm) * silu_f(zv));
  }
}

// ---------------- final (B,L,C) -> (B,C,H,W) transpose ------------------------
__global__ void __launch_bounds__(256) k_out_transpose(
    const float* __restrict__ yfin, float* __restrict__ out)
{
  int bc = blockIdx.x;
  int b = bc >> 7; int c = bc & 127;
  for (int l = threadIdx.x; l < LL; l += 256)
    out[(size_t)bc * LL + l] = yfin[((size_t)(b << 12) + l) * CDM + c];
}

extern "C" void kernel_launch(void* const* d_in, const int* in_sizes, int n_in,
                              void* d_out, int out_size, void* d_ws, size_t ws_size,
                              hipStream_t stream) {
  const float* x          = (const float*)d_in[0];
  const float* norm1_g    = (const float*)d_in[1];
  const float* norm1_b    = (const float*)d_in[2];
  const float* in_proj_w  = (const float*)d_in[3];
  const float* dwconv_w   = (const float*)d_in[4];
  const float* m_in_w     = (const float*)d_in[5];
  const float* m_conv_w   = (const float*)d_in[6];
  const float* m_conv_b   = (const float*)d_in[7];
  const float* m_xproj_w  = (const float*)d_in[8];
  const float* m_dt_w     = (const float*)d_in[9];
  const float* m_dt_b     = (const float*)d_in[10];
  const float* m_A_log    = (const float*)d_in[11];
  const float* m_D        = (const float*)d_in[12];
  const float* m_out_w    = (const float*)d_in[13];
  const float* normss_g   = (const float*)d_in[14];
  const float* normss_b   = (const float*)d_in[15];
  const float* out_proj_w = (const float*)d_in[16];
  const float* norm2_g    = (const float*)d_in[17];
  const float* norm2_b    = (const float*)d_in[18];
  const float* ffn_w1     = (const float*)d_in[19];
  const float* ffn_w2     = (const float*)d_in[20];

  float* ws = (float*)d_ws;
  size_t o = 0;
  auto alloc = [&](size_t nf) { float* p = ws + o; o += nf; return p; };
  const size_t BL = (size_t)B_N * LL;       // 16384
  // fp32 buffers
  float* xflat = alloc(BL * CDM);
  float* hbuf  = alloc(BL * DI);     // in_proj out (f32, dwconv input)
  float* xz    = alloc(BL * 2 * DI);
  float* xmc   = alloc(BL * DI);
  float* dt    = alloc(BL * DI);
  float* xbc   = alloc(BL * 8);
  float* ycomb = alloc(BL * DI);
  float* x2    = alloc(BL * CDM);
  float* yfin  = alloc(BL * CDM);
  float* Pbuf  = alloc((size_t)B_N * NC * DI * DS);
  float* Hbuf  = alloc((size_t)B_N * NC * DI * DS);
  // bf16 buffers (carved from float region; 2 ushorts per float slot)
  auto ualloc = [&](size_t nu) { ushort* p = (ushort*)(ws + o); o += (nu + 1) / 2; return p; };
  ushort* x1b   = ualloc(BL * CDM);
  ushort* hcb   = ualloc(BL * DI);
  ushort* ybufb = ualloc(BL * DI);
  ushort* hbufb = ualloc(BL * DI);
  ushort* x3b   = ualloc(BL * CDM);
  ushort* f1b   = ualloc(BL * CDM);
  ushort* wb    = ualloc(925696);    // all bf16 weights, segment offsets below
  ushort* w_inproj = wb + 0;
  ushort* w_min    = wb + 32768;     // 4 x (512,256)
  ushort* w_mout   = wb + 557056;    // 4 x (256,256)
  ushort* w_oproj  = wb + 819200;
  ushort* w_ffn1   = wb + 851968;
  ushort* w_ffn2   = wb + 868352;
  ushort* w_xproj  = wb + 884736;    // 4 x (24,256)
  ushort* w_dtw    = wb + 909312;    // 4 x (256,16)

  // 0. weights -> bf16
  k_cvt<<<(925696 / 4 + 255) / 256, 256, 0, stream>>>(
      in_proj_w, m_in_w, m_out_w, out_proj_w, ffn_w1, ffn_w2, m_xproj_w, m_dt_w, wb);
  // 1. transpose + LN1 -> x1b (bf16), xflat (f32)
  k_ln1<<<B_N * LL, CDM, 0, stream>>>(x, norm1_g, norm1_b, xflat, x1b);
  // 2. in_proj (M=16384,K=128,N=256) -> hbuf f32
  k_mgemm<0, 0><<<dim3(128, 2), 256, 0, stream>>>(
      x1b, CDM, w_inproj, hbuf, nullptr, DI, CDM, 0, nullptr);
  // 3. dw 3x3 conv + silu -> hcb bf16
  k_dwconv<<<B_N * LL, DI, 0, stream>>>(hbuf, dwconv_w, hcb);
  // 4. zero y_comb
  hipMemsetAsync(ycomb, 0, BL * DI * sizeof(float), stream);
  // 5. per-direction mamba
  for (int dir = 0; dir < 4; ++dir) {
    k_mgemm<1, 0><<<dim3(128, 4), 256, 0, stream>>>(
        hcb, DI, w_min + (size_t)dir * 2 * DI * DI, xz, nullptr, 2 * DI, DI, dir, nullptr);
    k_conv1d<<<B_N * LL, DI, 0, stream>>>(
        xz, m_conv_w + (size_t)dir * DI * DCV, m_conv_b + (size_t)dir * DI, xmc);
    k_xproj_dt<<<B_N * LL / 4, 256, 0, stream>>>(
        xmc, w_xproj + (size_t)dir * 24 * DI, w_dtw + (size_t)dir * DI * DTR,
        m_dt_b + (size_t)dir * DI, dt, xbc);
    const float* Alog_d = m_A_log + (size_t)dir * DI * DS;
    k_scan_part<<<B_N * NC, 256, 0, stream>>>(dt, xmc, xbc, Alog_d, Pbuf, Hbuf);
    k_scan_carry<<<16, 256, 0, stream>>>(Pbuf, Hbuf);
    k_scan_fix<<<B_N * NC, 256, 0, stream>>>(
        dt, xmc, xbc, xz, Alog_d, m_D + (size_t)dir * DI, Hbuf, ybufb);
    k_mgemm<0, 2><<<dim3(128, 2), 256, 0, stream>>>(
        ybufb, DI, w_mout + (size_t)dir * DI * DI, ycomb, nullptr, DI, DI, dir, nullptr);
  }
  // 6. LN over 256 -> hbufb bf16
  k_ln<DI><<<B_N * LL, DI, 0, stream>>>(ycomb, normss_g, normss_b, hbufb);
  // 7. out_proj + residual(xflat) -> x2 f32
  k_mgemm<0, 3><<<dim3(128, 1), 256, 0, stream>>>(
      hbufb, DI, w_oproj, x2, nullptr, CDM, DI, 0, xflat);
  // 8. LN2 -> x3b bf16
  k_ln<CDM><<<B_N * LL, CDM, 0, stream>>>(x2, norm2_g, norm2_b, x3b);
  // 9. ffn1 + gelu -> f1b bf16
  k_mgemm<0, 4><<<dim3(128, 1), 256, 0, stream>>>(
      x3b, CDM, w_ffn1, nullptr, f1b, CDM, CDM, 0, nullptr);
  // 10. ffn2 + residual(x2) -> yfin f32
  k_mgemm<0, 3><<<dim3(128, 1), 256, 0, stream>>>(
      f1b, CDM, w_ffn2, yfin, nullptr, CDM, CDM, 0, x2);
  // 11. transpose out
  k_out_transpose<<<B_N * CDM, 256, 0, stream>>>(yfin, (float*)d_out);
}

// Round 4
// 556.374 us; speedup vs baseline: 18.5724x; 1.0886x over previous
//
#include <hip/hip_runtime.h>
#include <math.h>

// VSSBlock on MI355X — round 3:
//  - k_xproj_dt (164us, VALU-bound) removed: dt = MFMA GEMM with folded
//    (dt_w @ xproj_w[:16]) weight; B/C fused into conv1d block reduce.
//  - xz / in_proj / y_dir streams -> bf16; ycomb RMW+memset -> 4-way LN sum.
//  - LDS-tiled transposes for LN1 and final output (were ~16x overfetch).

#define B_N   4
#define CDM   128
#define HH    64
#define WW    64
#define LL    4096
#define DI    256
#define DS    4
#define DCV   4
#define DTR   16
#define CS    32
#define NC    (LL / CS)

typedef float    f32x4  __attribute__((ext_vector_type(4)));
typedef __bf16   bf16x8 __attribute__((ext_vector_type(8)));

__device__ __forceinline__ float silu_f(float x) { return x / (1.f + __expf(-x)); }
__device__ __forceinline__ float softplus_f(float x) {
  return (x > 20.f) ? x : log1pf(expf(x));
}
__device__ __forceinline__ float gelu_f(float x) {
  return 0.5f * x * (1.f + erff(x * 0.70710678118654752f));
}
__device__ __forceinline__ ushort f2bf(float x) {
  unsigned u = __builtin_bit_cast(unsigned, x);
  u += 0x7fffu + ((u >> 16) & 1u);          // RNE
  return (ushort)(u >> 16);
}
__device__ __forceinline__ float bf2f(ushort u) {
  return __builtin_bit_cast(float, (unsigned)u << 16);
}

__device__ __forceinline__ int sigma_map(int dir, int t) {
  int tt = (dir & 1) ? (LL - 1 - t) : t;
  if (dir >= 2) tt = ((tt & 63) << 6) | (tt >> 6);
  return tt;
}

// ---------------- weight fp32 -> bf16 conversion (one pass, 8 segments) -------
__global__ void __launch_bounds__(256) k_cvt(
    const float* __restrict__ s0, const float* __restrict__ s1,
    const float* __restrict__ s2, const float* __restrict__ s3,
    const float* __restrict__ s4, const float* __restrict__ s5,
    const float* __restrict__ s6, const float* __restrict__ s7,
    ushort* __restrict__ dst)
{
  int i = (blockIdx.x * 256 + threadIdx.x) * 4;
  const float* s; int base;
  if      (i < 32768)  { s = s0; base = 0; }
  else if (i < 557056) { s = s1; base = 32768; }
  else if (i < 819200) { s = s2; base = 557056; }
  else if (i < 851968) { s = s3; base = 819200; }
  else if (i < 868352) { s = s4; base = 851968; }
  else if (i < 884736) { s = s5; base = 868352; }
  else if (i < 909312) { s = s6; base = 884736; }
  else if (i < 925696) { s = s7; base = 909312; }
  else return;
  float4 v = *(const float4*)(s + (i - base));
  dst[i+0] = f2bf(v.x); dst[i+1] = f2bf(v.y); dst[i+2] = f2bf(v.z); dst[i+3] = f2bf(v.w);
}

// ---------------- W_dt_eff[dir] = dt_w (256,16) @ xproj_w[:16] (16,256) -------
__global__ void __launch_bounds__(256) k_dteff(
    const float* __restrict__ dtw, const float* __restrict__ xpw,
    ushort* __restrict__ out)
{
  int idx = blockIdx.x * 256 + threadIdx.x;   // dir*65536 + n*256 + k
  int dir = idx >> 16; int n = (idx >> 8) & 255; int k = idx & 255;
  const float* dw = dtw + ((size_t)dir * DI + n) * DTR;
  const float* xp = xpw + (size_t)dir * 24 * DI + k;
  float acc = 0.f;
  #pragma unroll
  for (int j = 0; j < DTR; ++j) acc += dw[j] * xp[j * DI];
  out[idx] = f2bf(acc);
}

// ---------------- LN1: tiled NCHW->(B,L,C) transpose + LayerNorm --------------
// block: 64 l-positions x 128 c. 256 threads.
__global__ void __launch_bounds__(256) k_ln1(
    const float* __restrict__ x, const float* __restrict__ g,
    const float* __restrict__ be, float* __restrict__ xflat,
    ushort* __restrict__ x1b)
{
  int blk = blockIdx.x;
  int b = blk >> 6; int l0 = (blk & 63) << 6;
  __shared__ float T[64][129];
  __shared__ float mrow[64], rrow[64];
  int t = threadIdx.x;
  int wv = t >> 6, lane = t & 63;
  for (int c = wv; c < CDM; c += 4)
    T[lane][c] = x[((size_t)b * CDM + c) * LL + l0 + lane];
  __syncthreads();
  int row = t >> 2, seg = t & 3;
  float s = 0.f;
  #pragma unroll
  for (int j = 0; j < 32; ++j) s += T[row][seg * 32 + j];
  s += __shfl_xor(s, 1); s += __shfl_xor(s, 2);
  float mean = s * (1.f / CDM);
  float v2 = 0.f;
  #pragma unroll
  for (int j = 0; j < 32; ++j) { float d = T[row][seg * 32 + j] - mean; v2 += d * d; }
  v2 += __shfl_xor(v2, 1); v2 += __shfl_xor(v2, 2);
  if (seg == 0) { mrow[row] = mean; rrow[row] = rsqrtf(v2 * (1.f / CDM) + 1e-5f); }
  __syncthreads();
  int c = t & 127;
  float gc = g[c], bc = be[c];
  for (int r = (t >> 7); r < 64; r += 2) {
    float v = T[r][c];
    size_t o = ((size_t)(b << 12) + l0 + r) * CDM + c;
    xflat[o] = v;
    x1b[o] = f2bf((v - mrow[r]) * rrow[r] * gc + bc);
  }
}

// ---------------- row LayerNorm f32 -> bf16 -----------------------------------
template<int WIDTH>
__global__ void __launch_bounds__(WIDTH) k_ln(
    const float* __restrict__ in, const float* __restrict__ g,
    const float* __restrict__ be, ushort* __restrict__ out)
{
  int row = blockIdx.x;
  int c = threadIdx.x;
  float v = in[(size_t)row * WIDTH + c];
  __shared__ float red[WIDTH];
  red[c] = v; __syncthreads();
  #pragma unroll
  for (int s = WIDTH / 2; s > 0; s >>= 1) { if (c < s) red[c] += red[c + s]; __syncthreads(); }
  float mean = red[0] * (1.f / WIDTH);
  __syncthreads();
  float dv = v - mean;
  red[c] = dv * dv; __syncthreads();
  #pragma unroll
  for (int s = WIDTH / 2; s > 0; s >>= 1) { if (c < s) red[c] += red[c + s]; __syncthreads(); }
  float var = red[0] * (1.f / WIDTH);
  out[(size_t)row * WIDTH + c] = f2bf(dv * rsqrtf(var + 1e-5f) * g[c] + be[c]);
}

// ---------------- 4-input-sum LayerNorm (bf16 in/out), width 256 --------------
__global__ void __launch_bounds__(DI) k_ln4(
    const ushort* __restrict__ y0, const ushort* __restrict__ y1,
    const ushort* __restrict__ y2, const ushort* __restrict__ y3,
    const float* __restrict__ g, const float* __restrict__ be,
    ushort* __restrict__ out)
{
  int row = blockIdx.x;
  int c = threadIdx.x;
  size_t off = (size_t)row * DI + c;
  float v = bf2f(y0[off]) + bf2f(y1[off]) + bf2f(y2[off]) + bf2f(y3[off]);
  __shared__ float red[DI];
  red[c] = v; __syncthreads();
  #pragma unroll
  for (int s = DI / 2; s > 0; s >>= 1) { if (c < s) red[c] += red[c + s]; __syncthreads(); }
  float mean = red[0] * (1.f / DI);
  __syncthreads();
  float dv = v - mean;
  red[c] = dv * dv; __syncthreads();
  #pragma unroll
  for (int s = DI / 2; s > 0; s >>= 1) { if (c < s) red[c] += red[c + s]; __syncthreads(); }
  float var = red[0] * (1.f / DI);
  out[off] = f2bf(dv * rsqrtf(var + 1e-5f) * g[c] + be[c]);
}

// ---------------- bf16 MFMA GEMM: C(M,N) = A(M,K) @ Wt(N,K)^T -----------------
// 128x128 tile, BK=64, 4 waves. GATHER=1: A rows via sigma_map(dir,t).
// EPI: 0 f32 store | 2 bf16 scatter 0.25v | 3 f32 aux(resid)+v | 4 bf16 gelu
//      5 f32 softplus(v+aux[col]) | 6 bf16 store
template<int GATHER, int EPI>
__global__ void __launch_bounds__(256) k_mgemm(
    const ushort* __restrict__ A, int lda,
    const ushort* __restrict__ Wt,
    float* __restrict__ Cf, ushort* __restrict__ Cb,
    int ldc, int K, int dir, const float* __restrict__ aux)
{
  __shared__ ushort As[128 * 64];
  __shared__ ushort Ws[128 * 64];
  int tid = threadIdx.x;
  int m0 = blockIdx.x << 7, n0 = blockIdx.y << 7;
  int lane = tid & 63;
  int wm = ((tid >> 7) & 1) * 64;
  int wn = ((tid >> 6) & 1) * 64;
  int r15 = lane & 15, khi = lane >> 4;

  int srow = tid >> 3;
  int scol = (tid & 7) << 3;
  int arow[4];
  #pragma unroll
  for (int i = 0; i < 4; ++i) {
    int r = m0 + i * 32 + srow;
    if (GATHER) { int b = r >> 12; int t = r & (LL - 1); r = (b << 12) + sigma_map(dir, t); }
    arow[i] = r;
  }
  int wrow[4];
  #pragma unroll
  for (int i = 0; i < 4; ++i) wrow[i] = n0 + i * 32 + srow;

  f32x4 acc[4][4] = {};
  int wavebase = (tid & 192) * 8;

  for (int ks = 0; ks < K; ks += 64) {
    if (ks) __syncthreads();
    #pragma unroll
    for (int i = 0; i < 4; ++i) {
      const ushort* gA = A + (size_t)arow[i] * lda + ks + scol;
      __builtin_amdgcn_global_load_lds(
          (const __attribute__((address_space(1))) void*)gA,
          (__attribute__((address_space(3))) void*)(As + i * 2048 + wavebase),
          16, 0, 0);
    }
    #pragma unroll
    for (int i = 0; i < 4; ++i) {
      const ushort* gW = Wt + (size_t)wrow[i] * K + ks + scol;
      __builtin_amdgcn_global_load_lds(
          (const __attribute__((address_space(1))) void*)gW,
          (__attribute__((address_space(3))) void*)(Ws + i * 2048 + wavebase),
          16, 0, 0);
    }
    __syncthreads();
    #pragma unroll
    for (int kk = 0; kk < 2; ++kk) {
      bf16x8 af[4], wf[4];
      #pragma unroll
      for (int mi = 0; mi < 4; ++mi)
        af[mi] = *(const bf16x8*)&As[(wm + mi * 16 + r15) * 64 + kk * 32 + khi * 8];
      #pragma unroll
      for (int ni = 0; ni < 4; ++ni)
        wf[ni] = *(const bf16x8*)&Ws[(wn + ni * 16 + r15) * 64 + kk * 32 + khi * 8];
      #pragma unroll
      for (int mi = 0; mi < 4; ++mi)
        #pragma unroll
        for (int ni = 0; ni < 4; ++ni)
          acc[mi][ni] = __builtin_amdgcn_mfma_f32_16x16x32_bf16(
              af[mi], wf[ni], acc[mi][ni], 0, 0, 0);
    }
  }

  #pragma unroll
  for (int mi = 0; mi < 4; ++mi) {
    #pragma unroll
    for (int j = 0; j < 4; ++j) {
      int row = m0 + wm + mi * 16 + khi * 4 + j;
      int orow = row;
      if (EPI == 2) { int b = row >> 12; int t = row & (LL - 1); orow = (b << 12) + sigma_map(dir, t); }
      #pragma unroll
      for (int ni = 0; ni < 4; ++ni) {
        int col = n0 + wn + ni * 16 + r15;
        size_t off = (size_t)orow * ldc + col;
        float v = acc[mi][ni][j];
        if      (EPI == 0) Cf[off] = v;
        else if (EPI == 2) Cb[off] = f2bf(0.25f * v);
        else if (EPI == 3) Cf[off] = aux[off] + v;
        else if (EPI == 4) Cb[off] = f2bf(gelu_f(v));
        else if (EPI == 5) Cf[off] = softplus_f(v + aux[col]);
        else if (EPI == 6) Cb[off] = f2bf(v);
      }
    }
  }
}

// ---------------- depthwise 3x3 conv (NHWC, bf16 in) + SiLU -> bf16 -----------
__global__ void __launch_bounds__(256) k_dwconv(
    const ushort* __restrict__ h, const float* __restrict__ wgt,
    ushort* __restrict__ out)
{
  int p = blockIdx.x;
  int b = p >> 12; int l = p & (LL - 1);
  int hy = l >> 6, wx = l & 63;
  int d = threadIdx.x;
  float acc = 0.f;
  #pragma unroll
  for (int di = -1; di <= 1; ++di) {
    int yy = hy + di; if (yy < 0 || yy >= HH) continue;
    #pragma unroll
    for (int dj = -1; dj <= 1; ++dj) {
      int xx = wx + dj; if (xx < 0 || xx >= WW) continue;
      acc += wgt[d * 9 + (di + 1) * 3 + (dj + 1)] *
             bf2f(h[(((size_t)b << 12) + (yy << 6) + xx) * DI + d]);
    }
  }
  out[(size_t)p * DI + d] = f2bf(silu_f(acc));
}

// ---------------- causal conv1d(k=4)+SiLU + fused B/C projection --------------
// block = 256 threads = all d of one row p; xbc via LDS + 32-lane reduce.
__global__ void __launch_bounds__(256) k_conv1d(
    const ushort* __restrict__ xzb, const float* __restrict__ cw,
    const float* __restrict__ cb, const ushort* __restrict__ xw8,
    ushort* __restrict__ xmcb, float* __restrict__ xbc)
{
  int p = blockIdx.x;
  int b = p >> 12; int t = p & (LL - 1);
  int d = threadIdx.x;
  float acc = cb[d];
  #pragma unroll
  for (int k = 0; k < DCV; ++k) {
    int tt = t - (DCV - 1) + k;
    if (tt >= 0)
      acc += cw[d * DCV + k] * bf2f(xzb[((size_t)(b << 12) + tt) * (2 * DI) + d]);
  }
  float xm = silu_f(acc);
  xmcb[(size_t)p * DI + d] = f2bf(xm);
  __shared__ float xsh[DI];
  xsh[d] = xm;
  __syncthreads();
  int n = d >> 5, j = d & 31;
  const ushort* wr = xw8 + n * DI;
  float s = 0.f;
  #pragma unroll
  for (int k = 0; k < 8; ++k) s += xsh[j + (k << 5)] * bf2f(wr[j + (k << 5)]);
  #pragma unroll
  for (int o = 1; o < 32; o <<= 1) s += __shfl_xor(s, o);
  if (j == 0) xbc[(size_t)p * 8 + n] = s;
}

// ================= chunked selective scan =====================================
__global__ void __launch_bounds__(256) k_scan_part(
    const float* __restrict__ dtbuf, const ushort* __restrict__ xmcb,
    const float* __restrict__ xbc, const float* __restrict__ Alog,
    float* __restrict__ Pbuf, float* __restrict__ Hbuf)
{
  int blk = blockIdx.x;
  int b = blk >> 7; int ch = blk & (NC - 1);
  int d = threadIdx.x;
  float Av[DS], h[DS], P[DS];
  #pragma unroll
  for (int n = 0; n < DS; ++n) { Av[n] = -expf(Alog[d * DS + n]); h[n] = 0.f; P[n] = 1.f; }
  size_t base = (size_t)b * LL + (size_t)ch * CS;
  #pragma unroll 4
  for (int t = 0; t < CS; ++t) {
    size_t r = base + t;
    float dt = dtbuf[r * DI + d];
    float xm = bf2f(xmcb[r * DI + d]);
    float4 Bv = *(const float4*)(xbc + r * 8);
    float bx = dt * xm;
    float dA0 = __expf(dt * Av[0]), dA1 = __expf(dt * Av[1]);
    float dA2 = __expf(dt * Av[2]), dA3 = __expf(dt * Av[3]);
    h[0] = dA0 * h[0] + bx * Bv.x; P[0] *= dA0;
    h[1] = dA1 * h[1] + bx * Bv.y; P[1] *= dA1;
    h[2] = dA2 * h[2] + bx * Bv.z; P[2] *= dA2;
    h[3] = dA3 * h[3] + bx * Bv.w; P[3] *= dA3;
  }
  size_t o = ((size_t)blk * DI + d) * DS;
  #pragma unroll
  for (int n = 0; n < DS; ++n) { Pbuf[o + n] = P[n]; Hbuf[o + n] = h[n]; }
}

__global__ void __launch_bounds__(256) k_scan_carry(
    const float* __restrict__ Pbuf, float* __restrict__ Hbuf)
{
  int idx = blockIdx.x * 256 + threadIdx.x;
  int b = idx >> 10; int dn = idx & 1023;
  float carry = 0.f;
  #pragma unroll 8
  for (int ch = 0; ch < NC; ++ch) {
    size_t o = (((size_t)b * NC + ch) * DI * DS) + dn;
    float Pv = Pbuf[o], Hv = Hbuf[o];
    Hbuf[o] = carry;
    carry = Pv * carry + Hv;
  }
}

__global__ void __launch_bounds__(256) k_scan_fix(
    const float* __restrict__ dtbuf, const ushort* __restrict__ xmcb,
    const float* __restrict__ xbc, const ushort* __restrict__ xzb,
    const float* __restrict__ Alog, const float* __restrict__ Dp,
    const float* __restrict__ Cin, ushort* __restrict__ ybuf)
{
  int blk = blockIdx.x;
  int b = blk >> 7; int ch = blk & (NC - 1);
  int d = threadIdx.x;
  float Av[DS], h[DS];
  size_t ci = ((size_t)blk * DI + d) * DS;
  #pragma unroll
  for (int n = 0; n < DS; ++n) { Av[n] = -expf(Alog[d * DS + n]); h[n] = Cin[ci + n]; }
  float Dv = Dp[d];
  size_t base = (size_t)b * LL + (size_t)ch * CS;
  #pragma unroll 4
  for (int t = 0; t < CS; ++t) {
    size_t r = base + t;
    float dt = dtbuf[r * DI + d];
    float xm = bf2f(xmcb[r * DI + d]);
    float4 Bv = *(const float4*)(xbc + r * 8);
    float4 Cv = *(const float4*)(xbc + r * 8 + 4);
    float bx = dt * xm;
    float dA0 = __expf(dt * Av[0]), dA1 = __expf(dt * Av[1]);
    float dA2 = __expf(dt * Av[2]), dA3 = __expf(dt * Av[3]);
    h[0] = dA0 * h[0] + bx * Bv.x;
    h[1] = dA1 * h[1] + bx * Bv.y;
    h[2] = dA2 * h[2] + bx * Bv.z;
    h[3] = dA3 * h[3] + bx * Bv.w;
    float y = h[0] * Cv.x + h[1] * Cv.y + h[2] * Cv.z + h[3] * Cv.w;
    float zv = bf2f(xzb[r * (2 * DI) + DI + d]);
    ybuf[r * DI + d] = f2bf((y + Dv * xm) * silu_f(zv));
  }
}

// ---------------- final (B,L,C)->(B,C,H,W) transpose, 64x64 LDS tile ----------
__global__ void __launch_bounds__(256) k_out_tr(
    const float* __restrict__ yfin, float* __restrict__ out)
{
  int b = blockIdx.x, c0 = blockIdx.y << 6, l0 = blockIdx.z << 6;
  __shared__ float T[64][65];
  int t = threadIdx.x;
  int q = t >> 6, lane = t & 63;
  for (int i = q; i < 64; i += 4)
    T[i][lane] = yfin[((size_t)(b << 12) + l0 + i) * CDM + c0 + lane];
  __syncthreads();
  for (int cc = q; cc < 64; cc += 4)
    out[(((size_t)b * CDM + c0 + cc) << 12) + l0 + lane] = T[lane][cc];
}

extern "C" void kernel_launch(void* const* d_in, const int* in_sizes, int n_in,
                              void* d_out, int out_size, void* d_ws, size_t ws_size,
                              hipStream_t stream) {
  const float* x          = (const float*)d_in[0];
  const float* norm1_g    = (const float*)d_in[1];
  const float* norm1_b    = (const float*)d_in[2];
  const float* in_proj_w  = (const float*)d_in[3];
  const float* dwconv_w   = (const float*)d_in[4];
  const float* m_in_w     = (const float*)d_in[5];
  const float* m_conv_w   = (const float*)d_in[6];
  const float* m_conv_b   = (const float*)d_in[7];
  const float* m_xproj_w  = (const float*)d_in[8];
  const float* m_dt_w     = (const float*)d_in[9];
  const float* m_dt_b     = (const float*)d_in[10];
  const float* m_A_log    = (const float*)d_in[11];
  const float* m_D        = (const float*)d_in[12];
  const float* m_out_w    = (const float*)d_in[13];
  const float* normss_g   = (const float*)d_in[14];
  const float* normss_b   = (const float*)d_in[15];
  const float* out_proj_w = (const float*)d_in[16];
  const float* norm2_g    = (const float*)d_in[17];
  const float* norm2_b    = (const float*)d_in[18];
  const float* ffn_w1     = (const float*)d_in[19];
  const float* ffn_w2     = (const float*)d_in[20];

  float* ws = (float*)d_ws;
  size_t o = 0;
  auto alloc = [&](size_t nf) { float* p = ws + o; o += nf; return p; };
  const size_t BL = (size_t)B_N * LL;       // 16384
  // f32 buffers
  float* xflat = alloc(BL * CDM);
  float* dt    = alloc(BL * DI);
  float* xbc   = alloc(BL * 8);
  float* x2    = alloc(BL * CDM);
  float* yfin  = alloc(BL * CDM);
  float* Pbuf  = alloc((size_t)B_N * NC * DI * DS);
  float* Hbuf  = alloc((size_t)B_N * NC * DI * DS);
  // bf16 buffers
  auto ualloc = [&](size_t nu) { ushort* p = (ushort*)(ws + o); o += (nu + 1) / 2; return p; };
  ushort* x1b   = ualloc(BL * CDM);
  ushort* hinb  = ualloc(BL * DI);       // in_proj out
  ushort* hcb   = ualloc(BL * DI);       // dwconv out
  ushort* xzb   = ualloc(BL * 2 * DI);
  ushort* xmcb  = ualloc(BL * DI);
  ushort* ybufb = ualloc(BL * DI);
  ushort* ydir  = ualloc(BL * DI * 4);   // 4 scattered per-dir outputs
  ushort* hlnb  = ualloc(BL * DI);       // ln4 out
  ushort* x3b   = ualloc(BL * CDM);
  ushort* f1b   = ualloc(BL * CDM);
  ushort* wb    = ualloc(925696);
  ushort* w_dteff = ualloc(4 * DI * DI); // folded dt weights
  ushort* w_inproj = wb + 0;
  ushort* w_min    = wb + 32768;
  ushort* w_mout   = wb + 557056;
  ushort* w_oproj  = wb + 819200;
  ushort* w_ffn1   = wb + 851968;
  ushort* w_ffn2   = wb + 868352;
  ushort* w_xproj  = wb + 884736;

  // 0. weights -> bf16; folded dt weight
  k_cvt<<<904, 256, 0, stream>>>(
      in_proj_w, m_in_w, m_out_w, out_proj_w, ffn_w1, ffn_w2, m_xproj_w, m_dt_w, wb);
  k_dteff<<<1024, 256, 0, stream>>>(m_dt_w, m_xproj_w, w_dteff);
  // 1. tiled transpose + LN1
  k_ln1<<<B_N * 64, 256, 0, stream>>>(x, norm1_g, norm1_b, xflat, x1b);
  // 2. in_proj -> bf16
  k_mgemm<0, 6><<<dim3(128, 2), 256, 0, stream>>>(
      x1b, CDM, w_inproj, nullptr, hinb, DI, CDM, 0, nullptr);
  // 3. dw 3x3 conv + silu
  k_dwconv<<<B_N * LL, DI, 0, stream>>>(hinb, dwconv_w, hcb);
  // 4. per-direction mamba
  for (int dir = 0; dir < 4; ++dir) {
    k_mgemm<1, 6><<<dim3(128, 4), 256, 0, stream>>>(
        hcb, DI, w_min + (size_t)dir * 2 * DI * DI, nullptr, xzb, 2 * DI, DI, dir, nullptr);
    k_conv1d<<<B_N * LL, 256, 0, stream>>>(
        xzb, m_conv_w + (size_t)dir * DI * DCV, m_conv_b + (size_t)dir * DI,
        w_xproj + (size_t)dir * 24 * DI + 16 * DI, xmcb, xbc);
    k_mgemm<0, 5><<<dim3(128, 2), 256, 0, stream>>>(
        xmcb, DI, w_dteff + (size_t)dir * DI * DI, dt, nullptr, DI, DI, 0,
        m_dt_b + (size_t)dir * DI);
    const float* Alog_d = m_A_log + (size_t)dir * DI * DS;
    k_scan_part<<<B_N * NC, 256, 0, stream>>>(dt, xmcb, xbc, Alog_d, Pbuf, Hbuf);
    k_scan_carry<<<16, 256, 0, stream>>>(Pbuf, Hbuf);
    k_scan_fix<<<B_N * NC, 256, 0, stream>>>(
        dt, xmcb, xbc, xzb, Alog_d, m_D + (size_t)dir * DI, Hbuf, ybufb);
    k_mgemm<0, 2><<<dim3(128, 2), 256, 0, stream>>>(
        ybufb, DI, w_mout + (size_t)dir * DI * DI, nullptr, ydir + (size_t)dir * BL * DI,
        DI, DI, dir, nullptr);
  }
  // 5. sum 4 dirs + LN
  k_ln4<<<B_N * LL, DI, 0, stream>>>(
      ydir, ydir + BL * DI, ydir + 2 * BL * DI, ydir + 3 * BL * DI,
      normss_g, normss_b, hlnb);
  // 6. out_proj + residual(xflat)
  k_mgemm<0, 3><<<dim3(128, 1), 256, 0, stream>>>(
      hlnb, DI, w_oproj, x2, nullptr, CDM, DI, 0, xflat);
  // 7. LN2
  k_ln<CDM><<<B_N * LL, CDM, 0, stream>>>(x2, norm2_g, norm2_b, x3b);
  // 8. ffn1 + gelu
  k_mgemm<0, 4><<<dim3(128, 1), 256, 0, stream>>>(
      x3b, CDM, w_ffn1, nullptr, f1b, CDM, CDM, 0, nullptr);
  // 9. ffn2 + residual(x2)
  k_mgemm<0, 3><<<dim3(128, 1), 256, 0, stream>>>(
      f1b, CDM, w_ffn2, yfin, nullptr, CDM, CDM, 0, x2);
  // 10. tiled transpose out
  k_out_tr<<<dim3(B_N, 2, 64), 256, 0, stream>>>(yfin, (float*)d_out);
}

// Round 5
// 405.135 us; speedup vs baseline: 25.5055x; 1.3733x over previous
//
#include <hip/hip_runtime.h>
#include <math.h>

// VSSBlock on MI355X — round 4: batched directions.
//  - single xz GEMM (N=2048, no gather); sigma moves to conv1d/scan_fix reads
//  - single 4-dir fused out GEMM (K=1024, inverse-sigma A gather), kills
//    scattered C writes + ln4
//  - conv1d / dt-GEMM / scan kernels batched over dir: 35 -> 18 launches
//  - dt stored bf16. ws total ~261MB of 256MiB.

#define B_N   4
#define CDM   128
#define HH    64
#define WW    64
#define LL    4096
#define DI    256
#define DS    4
#define DCV   4
#define DTR   16
#define CS    32
#define NC    (LL / CS)
#define BLT   16384          // B_N * LL

typedef float    f32x4  __attribute__((ext_vector_type(4)));
typedef __bf16   bf16x8 __attribute__((ext_vector_type(8)));

__device__ __forceinline__ float silu_f(float x) { return x / (1.f + __expf(-x)); }
__device__ __forceinline__ float softplus_f(float x) {
  return (x > 20.f) ? x : log1pf(expf(x));
}
__device__ __forceinline__ float gelu_f(float x) {
  return 0.5f * x * (1.f + erff(x * 0.70710678118654752f));
}
__device__ __forceinline__ ushort f2bf(float x) {
  unsigned u = __builtin_bit_cast(unsigned, x);
  u += 0x7fffu + ((u >> 16) & 1u);          // RNE
  return (ushort)(u >> 16);
}
__device__ __forceinline__ float bf2f(ushort u) {
  return __builtin_bit_cast(float, (unsigned)u << 16);
}

// dir-sequence position t -> original flat index l
__device__ __forceinline__ int sigma_map(int dir, int t) {
  int tt = (dir & 1) ? (LL - 1 - t) : t;
  if (dir >= 2) tt = ((tt & 63) << 6) | (tt >> 6);
  return tt;
}

// ---------------- weight fp32 -> bf16 conversion ------------------------------
__global__ void __launch_bounds__(256) k_cvt(
    const float* __restrict__ s0, const float* __restrict__ s1,
    const float* __restrict__ s2, const float* __restrict__ s3,
    const float* __restrict__ s4, const float* __restrict__ s5,
    const float* __restrict__ s6, const float* __restrict__ s7,
    ushort* __restrict__ dst)
{
  int i = (blockIdx.x * 256 + threadIdx.x) * 4;
  const float* s; int base;
  if      (i < 32768)  { s = s0; base = 0; }
  else if (i < 557056) { s = s1; base = 32768; }
  else if (i < 819200) { s = s2; base = 557056; }
  else if (i < 851968) { s = s3; base = 819200; }
  else if (i < 868352) { s = s4; base = 851968; }
  else if (i < 884736) { s = s5; base = 868352; }
  else if (i < 909312) { s = s6; base = 884736; }
  else if (i < 925696) { s = s7; base = 909312; }
  else return;
  float4 v = *(const float4*)(s + (i - base));
  dst[i+0] = f2bf(v.x); dst[i+1] = f2bf(v.y); dst[i+2] = f2bf(v.z); dst[i+3] = f2bf(v.w);
}

// ---------------- W_dt_eff[dir] = dt_w (256,16) @ xproj_w[:16] (16,256) -------
__global__ void __launch_bounds__(256) k_dteff(
    const float* __restrict__ dtw, const float* __restrict__ xpw,
    ushort* __restrict__ out)
{
  int idx = blockIdx.x * 256 + threadIdx.x;   // dir*65536 + n*256 + k
  int dir = idx >> 16; int n = (idx >> 8) & 255; int k = idx & 255;
  const float* dw = dtw + ((size_t)dir * DI + n) * DTR;
  const float* xp = xpw + (size_t)dir * 24 * DI + k;
  float acc = 0.f;
  #pragma unroll
  for (int j = 0; j < DTR; ++j) acc += dw[j] * xp[j * DI];
  out[idx] = f2bf(acc);
}

// ---------------- LN1: tiled NCHW->(B,L,C) transpose + LayerNorm --------------
__global__ void __launch_bounds__(256) k_ln1(
    const float* __restrict__ x, const float* __restrict__ g,
    const float* __restrict__ be, float* __restrict__ xflat,
    ushort* __restrict__ x1b)
{
  int blk = blockIdx.x;
  int b = blk >> 6; int l0 = (blk & 63) << 6;
  __shared__ float T[64][129];
  __shared__ float mrow[64], rrow[64];
  int t = threadIdx.x;
  int wv = t >> 6, lane = t & 63;
  for (int c = wv; c < CDM; c += 4)
    T[lane][c] = x[((size_t)b * CDM + c) * LL + l0 + lane];
  __syncthreads();
  int row = t >> 2, seg = t & 3;
  float s = 0.f;
  #pragma unroll
  for (int j = 0; j < 32; ++j) s += T[row][seg * 32 + j];
  s += __shfl_xor(s, 1); s += __shfl_xor(s, 2);
  float mean = s * (1.f / CDM);
  float v2 = 0.f;
  #pragma unroll
  for (int j = 0; j < 32; ++j) { float d = T[row][seg * 32 + j] - mean; v2 += d * d; }
  v2 += __shfl_xor(v2, 1); v2 += __shfl_xor(v2, 2);
  if (seg == 0) { mrow[row] = mean; rrow[row] = rsqrtf(v2 * (1.f / CDM) + 1e-5f); }
  __syncthreads();
  int c = t & 127;
  float gc = g[c], bc = be[c];
  for (int r = (t >> 7); r < 64; r += 2) {
    float v = T[r][c];
    size_t o = ((size_t)(b << 12) + l0 + r) * CDM + c;
    xflat[o] = v;
    x1b[o] = f2bf((v - mrow[r]) * rrow[r] * gc + bc);
  }
}

// ---------------- row LayerNorm f32 -> bf16 -----------------------------------
template<int WIDTH>
__global__ void __launch_bounds__(WIDTH) k_ln(
    const float* __restrict__ in, const float* __restrict__ g,
    const float* __restrict__ be, ushort* __restrict__ out)
{
  int row = blockIdx.x;
  int c = threadIdx.x;
  float v = in[(size_t)row * WIDTH + c];
  __shared__ float red[WIDTH];
  red[c] = v; __syncthreads();
  #pragma unroll
  for (int s = WIDTH / 2; s > 0; s >>= 1) { if (c < s) red[c] += red[c + s]; __syncthreads(); }
  float mean = red[0] * (1.f / WIDTH);
  __syncthreads();
  float dv = v - mean;
  red[c] = dv * dv; __syncthreads();
  #pragma unroll
  for (int s = WIDTH / 2; s > 0; s >>= 1) { if (c < s) red[c] += red[c + s]; __syncthreads(); }
  float var = red[0] * (1.f / WIDTH);
  out[(size_t)row * WIDTH + c] = f2bf(dv * rsqrtf(var + 1e-5f) * g[c] + be[c]);
}

// ---------------- row LayerNorm bf16 -> bf16, width 256 -----------------------
__global__ void __launch_bounds__(DI) k_lnb(
    const ushort* __restrict__ in, const float* __restrict__ g,
    const float* __restrict__ be, ushort* __restrict__ out)
{
  int row = blockIdx.x;
  int c = threadIdx.x;
  size_t off = (size_t)row * DI + c;
  float v = bf2f(in[off]);
  __shared__ float red[DI];
  red[c] = v; __syncthreads();
  #pragma unroll
  for (int s = DI / 2; s > 0; s >>= 1) { if (c < s) red[c] += red[c + s]; __syncthreads(); }
  float mean = red[0] * (1.f / DI);
  __syncthreads();
  float dv = v - mean;
  red[c] = dv * dv; __syncthreads();
  #pragma unroll
  for (int s = DI / 2; s > 0; s >>= 1) { if (c < s) red[c] += red[c + s]; __syncthreads(); }
  float var = red[0] * (1.f / DI);
  out[off] = f2bf(dv * rsqrtf(var + 1e-5f) * g[c] + be[c]);
}

// ---------------- bf16 MFMA GEMM ----------------------------------------------
// C(M,N) = A(M,K) @ Wt(N,K)^T. 128x128 tile, BK=64, 4 waves.
// GATHER: 0 none | 2 fused 4-dir out-GEMM (K=1024; A = 4 ybuf segments of
//         16384x256, row = inv_sigma(dir,l); Wt = 4 x (256,256) along K)
// EPI: 0 f32 store | 3 f32 aux(resid)+v | 4 bf16 gelu | 6 bf16 store
//      7 bf16 softplus(v+aux[col]) | 8 bf16 0.25*v
// BZ: 1 -> per-blockIdx.z dir offsets (dt GEMM batching)
template<int GATHER, int EPI, int BZ>
__global__ void __launch_bounds__(256) k_mgemm(
    const ushort* __restrict__ A, int lda,
    const ushort* __restrict__ Wt,
    float* __restrict__ Cf, ushort* __restrict__ Cb,
    int ldc, int K, const float* __restrict__ aux)
{
  if (BZ) {
    int z = blockIdx.z;
    A  += (size_t)z * BLT * DI;
    Wt += (size_t)z * DI * DI;
    if (Cb) Cb += (size_t)z * BLT * DI;
    if (Cf) Cf += (size_t)z * BLT * DI;
    if (aux) aux += (size_t)z * DI;
  }
  __shared__ ushort As[128 * 64];
  __shared__ ushort Ws[128 * 64];
  int tid = threadIdx.x;
  int m0 = blockIdx.x << 7, n0 = blockIdx.y << 7;
  int lane = tid & 63;
  int wm = ((tid >> 7) & 1) * 64;
  int wn = ((tid >> 6) & 1) * 64;
  int r15 = lane & 15, khi = lane >> 4;

  int srow = tid >> 3;
  int scol = (tid & 7) << 3;
  int arow[4];        // GATHER==0
  int arow2[4][4];    // GATHER==2: [i][dir]
  #pragma unroll
  for (int i = 0; i < 4; ++i) {
    int r = m0 + i * 32 + srow;
    if (GATHER == 2) {
      int b = r >> 12, l = r & (LL - 1);
      int tl = ((l & 63) << 6) | (l >> 6);
      arow2[i][0] = (b << 12) + l;
      arow2[i][1] = (b << 12) + (LL - 1 - l);
      arow2[i][2] = (b << 12) + tl;
      arow2[i][3] = (b << 12) + (LL - 1 - tl);
    } else arow[i] = r;
  }
  int wrow[4];
  #pragma unroll
  for (int i = 0; i < 4; ++i) wrow[i] = n0 + i * 32 + srow;

  f32x4 acc[4][4] = {};
  int wavebase = (tid & 192) * 8;

  for (int ks = 0; ks < K; ks += 64) {
    if (ks) __syncthreads();
    int dir = (GATHER == 2) ? (ks >> 8) : 0;
    int kin = (GATHER == 2) ? (ks & 255) : ks;
    #pragma unroll
    for (int i = 0; i < 4; ++i) {
      const ushort* gA = (GATHER == 2)
          ? A + (size_t)dir * (BLT * DI) + (size_t)arow2[i][dir] * DI + kin + scol
          : A + (size_t)arow[i] * lda + kin + scol;
      __builtin_amdgcn_global_load_lds(
          (const __attribute__((address_space(1))) void*)gA,
          (__attribute__((address_space(3))) void*)(As + i * 2048 + wavebase),
          16, 0, 0);
    }
    #pragma unroll
    for (int i = 0; i < 4; ++i) {
      const ushort* gW = (GATHER == 2)
          ? Wt + (size_t)dir * (DI * DI) + (size_t)wrow[i] * DI + kin + scol
          : Wt + (size_t)wrow[i] * K + kin + scol;
      __builtin_amdgcn_global_load_lds(
          (const __attribute__((address_space(1))) void*)gW,
          (__attribute__((address_space(3))) void*)(Ws + i * 2048 + wavebase),
          16, 0, 0);
    }
    __syncthreads();
    #pragma unroll
    for (int kk = 0; kk < 2; ++kk) {
      bf16x8 af[4], wf[4];
      #pragma unroll
      for (int mi = 0; mi < 4; ++mi)
        af[mi] = *(const bf16x8*)&As[(wm + mi * 16 + r15) * 64 + kk * 32 + khi * 8];
      #pragma unroll
      for (int ni = 0; ni < 4; ++ni)
        wf[ni] = *(const bf16x8*)&Ws[(wn + ni * 16 + r15) * 64 + kk * 32 + khi * 8];
      #pragma unroll
      for (int mi = 0; mi < 4; ++mi)
        #pragma unroll
        for (int ni = 0; ni < 4; ++ni)
          acc[mi][ni] = __builtin_amdgcn_mfma_f32_16x16x32_bf16(
              af[mi], wf[ni], acc[mi][ni], 0, 0, 0);
    }
  }

  #pragma unroll
  for (int mi = 0; mi < 4; ++mi) {
    #pragma unroll
    for (int j = 0; j < 4; ++j) {
      int row = m0 + wm + mi * 16 + khi * 4 + j;
      #pragma unroll
      for (int ni = 0; ni < 4; ++ni) {
        int col = n0 + wn + ni * 16 + r15;
        size_t off = (size_t)row * ldc + col;
        float v = acc[mi][ni][j];
        if      (EPI == 0) Cf[off] = v;
        else if (EPI == 3) Cf[off] = aux[off] + v;
        else if (EPI == 4) Cb[off] = f2bf(gelu_f(v));
        else if (EPI == 6) Cb[off] = f2bf(v);
        else if (EPI == 7) Cb[off] = f2bf(softplus_f(v + aux[col]));
        else if (EPI == 8) Cb[off] = f2bf(0.25f * v);
      }
    }
  }
}

// ---------------- depthwise 3x3 conv (NHWC, bf16 in) + SiLU -> bf16 -----------
__global__ void __launch_bounds__(256) k_dwconv(
    const ushort* __restrict__ h, const float* __restrict__ wgt,
    ushort* __restrict__ out)
{
  int p = blockIdx.x;
  int b = p >> 12; int l = p & (LL - 1);
  int hy = l >> 6, wx = l & 63;
  int d = threadIdx.x;
  float acc = 0.f;
  #pragma unroll
  for (int di = -1; di <= 1; ++di) {
    int yy = hy + di; if (yy < 0 || yy >= HH) continue;
    #pragma unroll
    for (int dj = -1; dj <= 1; ++dj) {
      int xx = wx + dj; if (xx < 0 || xx >= WW) continue;
      acc += wgt[d * 9 + (di + 1) * 3 + (dj + 1)] *
             bf2f(h[(((size_t)b << 12) + (yy << 6) + xx) * DI + d]);
    }
  }
  out[(size_t)p * DI + d] = f2bf(silu_f(acc));
}

// ---------------- causal conv1d + SiLU + fused B/C projection, all dirs -------
// grid = 4 * BLT blocks; reads xz_all via sigma gather (coalesced in d).
__global__ void __launch_bounds__(256) k_conv1d4(
    const ushort* __restrict__ xz_all, const float* __restrict__ cw,
    const float* __restrict__ cb, const ushort* __restrict__ xpw,
    ushort* __restrict__ xmc4, float* __restrict__ xbc4)
{
  int blk = blockIdx.x;
  int dir = blk >> 14; int p = blk & (BLT - 1);
  int b = p >> 12; int t = p & (LL - 1);
  int d = threadIdx.x;
  const float* cwd = cw + dir * DI * DCV + d * DCV;
  float acc = cb[dir * DI + d];
  #pragma unroll
  for (int k = 0; k < DCV; ++k) {
    int tt = t - (DCV - 1) + k;
    if (tt >= 0) {
      int l = sigma_map(dir, tt);
      acc += cwd[k] * bf2f(xz_all[(((size_t)(b << 12)) + l) * 2048 + (dir << 9) + d]);
    }
  }
  float xm = silu_f(acc);
  xmc4[((size_t)dir * BLT + p) * DI + d] = f2bf(xm);
  __shared__ float xsh[DI];
  xsh[d] = xm;
  __syncthreads();
  int n = d >> 5, j = d & 31;
  const ushort* wr = xpw + (size_t)dir * 24 * DI + 16 * DI + n * DI;
  float s = 0.f;
  #pragma unroll
  for (int k = 0; k < 8; ++k) s += xsh[j + (k << 5)] * bf2f(wr[j + (k << 5)]);
  #pragma unroll
  for (int o = 1; o < 32; o <<= 1) s += __shfl_xor(s, o);
  if (j == 0) xbc4[((size_t)dir * BLT + p) * 8 + n] = s;
}

// ================= chunked selective scan (batched over dirs) =================
__global__ void __launch_bounds__(256) k_scan_part(
    const ushort* __restrict__ dt4, const ushort* __restrict__ xmc4,
    const float* __restrict__ xbc4, const float* __restrict__ Alog4,
    float* __restrict__ P4, float* __restrict__ H4)
{
  int blk = blockIdx.x;                  // dir*512 + b*128 + ch
  int dir = blk >> 9; int b = (blk >> 7) & 3; int ch = blk & (NC - 1);
  int d = threadIdx.x;
  const float* Alog = Alog4 + (size_t)dir * DI * DS;
  float Av[DS], h[DS], P[DS];
  #pragma unroll
  for (int n = 0; n < DS; ++n) { Av[n] = -expf(Alog[d * DS + n]); h[n] = 0.f; P[n] = 1.f; }
  size_t seg = (size_t)dir * BLT;
  size_t base = seg + (size_t)b * LL + (size_t)ch * CS;
  #pragma unroll 4
  for (int t = 0; t < CS; ++t) {
    size_t r = base + t;
    float dt = bf2f(dt4[r * DI + d]);
    float xm = bf2f(xmc4[r * DI + d]);
    float4 Bv = *(const float4*)(xbc4 + r * 8);
    float bx = dt * xm;
    float dA0 = __expf(dt * Av[0]), dA1 = __expf(dt * Av[1]);
    float dA2 = __expf(dt * Av[2]), dA3 = __expf(dt * Av[3]);
    h[0] = dA0 * h[0] + bx * Bv.x; P[0] *= dA0;
    h[1] = dA1 * h[1] + bx * Bv.y; P[1] *= dA1;
    h[2] = dA2 * h[2] + bx * Bv.z; P[2] *= dA2;
    h[3] = dA3 * h[3] + bx * Bv.w; P[3] *= dA3;
  }
  size_t o = ((size_t)blk * DI + d) * DS;
  #pragma unroll
  for (int n = 0; n < DS; ++n) { P4[o + n] = P[n]; H4[o + n] = h[n]; }
}

__global__ void __launch_bounds__(256) k_scan_carry(
    const float* __restrict__ P4, float* __restrict__ H4)
{
  int idx = blockIdx.x * 256 + threadIdx.x;   // 0 .. 4*B*DI*DS-1 (16384)
  int dir = idx >> 12; int r = idx & 4095;
  int b = r >> 10; int dn = r & 1023;
  size_t sbase = ((size_t)dir * 512 + (size_t)b * NC) * 1024 + dn;
  float carry = 0.f;
  #pragma unroll 8
  for (int ch = 0; ch < NC; ++ch) {
    size_t o = sbase + (size_t)ch * 1024;
    float Pv = P4[o], Hv = H4[o];
    H4[o] = carry;
    carry = Pv * carry + Hv;
  }
}

__global__ void __launch_bounds__(256) k_scan_fix(
    const ushort* __restrict__ dt4, const ushort* __restrict__ xmc4,
    const float* __restrict__ xbc4, const ushort* __restrict__ xz_all,
    const float* __restrict__ Alog4, const float* __restrict__ Dp4,
    const float* __restrict__ Cin, ushort* __restrict__ ybuf4)
{
  int blk = blockIdx.x;
  int dir = blk >> 9; int b = (blk >> 7) & 3; int ch = blk & (NC - 1);
  int d = threadIdx.x;
  const float* Alog = Alog4 + (size_t)dir * DI * DS;
  float Av[DS], h[DS];
  size_t ci = ((size_t)blk * DI + d) * DS;
  #pragma unroll
  for (int n = 0; n < DS; ++n) { Av[n] = -expf(Alog[d * DS + n]); h[n] = Cin[ci + n]; }
  float Dv = Dp4[dir * DI + d];
  size_t seg = (size_t)dir * BLT;
  size_t base = seg + (size_t)b * LL + (size_t)ch * CS;
  #pragma unroll 4
  for (int t = 0; t < CS; ++t) {
    size_t r = base + t;
    float dt = bf2f(dt4[r * DI + d]);
    float xm = bf2f(xmc4[r * DI + d]);
    float4 Bv = *(const float4*)(xbc4 + r * 8);
    float4 Cv = *(const float4*)(xbc4 + r * 8 + 4);
    float bx = dt * xm;
    float dA0 = __expf(dt * Av[0]), dA1 = __expf(dt * Av[1]);
    float dA2 = __expf(dt * Av[2]), dA3 = __expf(dt * Av[3]);
    h[0] = dA0 * h[0] + bx * Bv.x;
    h[1] = dA1 * h[1] + bx * Bv.y;
    h[2] = dA2 * h[2] + bx * Bv.z;
    h[3] = dA3 * h[3] + bx * Bv.w;
    float y = h[0] * Cv.x + h[1] * Cv.y + h[2] * Cv.z + h[3] * Cv.w;
    int l = sigma_map(dir, ch * CS + t);
    float zv = bf2f(xz_all[(((size_t)(b << 12)) + l) * 2048 + (dir << 9) + 256 + d]);
    ybuf4[r * DI + d] = f2bf((y + Dv * xm) * silu_f(zv));
  }
}

// ---------------- final (B,L,C)->(B,C,H,W) transpose, 64x64 LDS tile ----------
__global__ void __launch_bounds__(256) k_out_tr(
    const float* __restrict__ yfin, float* __restrict__ out)
{
  int b = blockIdx.x, c0 = blockIdx.y << 6, l0 = blockIdx.z << 6;
  __shared__ float T[64][65];
  int t = threadIdx.x;
  int q = t >> 6, lane = t & 63;
  for (int i = q; i < 64; i += 4)
    T[i][lane] = yfin[((size_t)(b << 12) + l0 + i) * CDM + c0 + lane];
  __syncthreads();
  for (int cc = q; cc < 64; cc += 4)
    out[(((size_t)b * CDM + c0 + cc) << 12) + l0 + lane] = T[lane][cc];
}

extern "C" void kernel_launch(void* const* d_in, const int* in_sizes, int n_in,
                              void* d_out, int out_size, void* d_ws, size_t ws_size,
                              hipStream_t stream) {
  const float* x          = (const float*)d_in[0];
  const float* norm1_g    = (const float*)d_in[1];
  const float* norm1_b    = (const float*)d_in[2];
  const float* in_proj_w  = (const float*)d_in[3];
  const float* dwconv_w   = (const float*)d_in[4];
  const float* m_in_w     = (const float*)d_in[5];
  const float* m_conv_w   = (const float*)d_in[6];
  const float* m_conv_b   = (const float*)d_in[7];
  const float* m_xproj_w  = (const float*)d_in[8];
  const float* m_dt_w     = (const float*)d_in[9];
  const float* m_dt_b     = (const float*)d_in[10];
  const float* m_A_log    = (const float*)d_in[11];
  const float* m_D        = (const float*)d_in[12];
  const float* m_out_w    = (const float*)d_in[13];
  const float* normss_g   = (const float*)d_in[14];
  const float* normss_b   = (const float*)d_in[15];
  const float* out_proj_w = (const float*)d_in[16];
  const float* norm2_g    = (const float*)d_in[17];
  const float* norm2_b    = (const float*)d_in[18];
  const float* ffn_w1     = (const float*)d_in[19];
  const float* ffn_w2     = (const float*)d_in[20];

  float* ws = (float*)d_ws;
  size_t o = 0;
  auto alloc = [&](size_t nf) { float* p = ws + o; o += nf; return p; };
  const size_t BL = BLT;
  // f32 buffers (11.0M floats)
  float* xflat = alloc(BL * CDM);
  float* x2    = alloc(BL * CDM);
  float* yfin  = alloc(BL * CDM);
  float* xbc4  = alloc(BL * 8 * 4);
  float* P4    = alloc((size_t)4 * B_N * NC * DI * DS);
  float* H4    = alloc((size_t)4 * B_N * NC * DI * DS);
  // bf16 buffers (108.4M ushorts = 54.2M float slots); total ~261MB <= 256MiB
  auto ualloc = [&](size_t nu) { ushort* p = (ushort*)(ws + o); o += (nu + 1) / 2; return p; };
  ushort* x1b    = ualloc(BL * CDM);
  ushort* hinb   = ualloc(BL * DI);
  ushort* hcb    = ualloc(BL * DI);
  ushort* xz_all = ualloc(BL * 2048);
  ushort* xmc4   = ualloc(BL * DI * 4);
  ushort* dt4    = ualloc(BL * DI * 4);
  ushort* ybuf4  = ualloc(BL * DI * 4);
  ushort* ycombb = ualloc(BL * DI);
  ushort* hlnb   = ualloc(BL * DI);
  ushort* x3b    = ualloc(BL * CDM);
  ushort* f1b    = ualloc(BL * CDM);
  ushort* wb     = ualloc(925696);
  ushort* w_dteff = ualloc(4 * DI * DI);
  ushort* w_inproj = wb + 0;
  ushort* w_min    = wb + 32768;      // (2048,256) = all 4 dirs' in_w, N-major
  ushort* w_mout   = wb + 557056;     // 4 x (256,256)
  ushort* w_oproj  = wb + 819200;
  ushort* w_ffn1   = wb + 851968;
  ushort* w_ffn2   = wb + 868352;
  ushort* w_xproj  = wb + 884736;

  // 0. weights -> bf16; folded dt weight
  k_cvt<<<904, 256, 0, stream>>>(
      in_proj_w, m_in_w, m_out_w, out_proj_w, ffn_w1, ffn_w2, m_xproj_w, m_dt_w, wb);
  k_dteff<<<1024, 256, 0, stream>>>(m_dt_w, m_xproj_w, w_dteff);
  // 1. tiled transpose + LN1
  k_ln1<<<B_N * 64, 256, 0, stream>>>(x, norm1_g, norm1_b, xflat, x1b);
  // 2. in_proj -> bf16
  k_mgemm<0, 6, 0><<<dim3(128, 2), 256, 0, stream>>>(
      x1b, CDM, w_inproj, nullptr, hinb, DI, CDM, nullptr);
  // 3. dw 3x3 conv + silu
  k_dwconv<<<B_N * LL, DI, 0, stream>>>(hinb, dwconv_w, hcb);
  // 4. xz for ALL dirs: (16384,2048) = hcb @ w_min^T, natural row order
  k_mgemm<0, 6, 0><<<dim3(128, 16), 256, 0, stream>>>(
      hcb, DI, w_min, nullptr, xz_all, 2048, DI, nullptr);
  // 5. conv1d + B/C, all dirs
  k_conv1d4<<<4 * B_N * LL, 256, 0, stream>>>(
      xz_all, m_conv_w, m_conv_b, w_xproj, xmc4, xbc4);
  // 6. dt GEMM, batched over dirs via blockIdx.z
  k_mgemm<0, 7, 1><<<dim3(128, 2, 4), 256, 0, stream>>>(
      xmc4, DI, w_dteff, nullptr, dt4, DI, DI, m_dt_b);
  // 7. chunked scan, all dirs
  k_scan_part<<<4 * B_N * NC, 256, 0, stream>>>(dt4, xmc4, xbc4, m_A_log, P4, H4);
  k_scan_carry<<<64, 256, 0, stream>>>(P4, H4);
  k_scan_fix<<<4 * B_N * NC, 256, 0, stream>>>(
      dt4, xmc4, xbc4, xz_all, m_A_log, m_D, H4, ybuf4);
  // 8. fused 4-dir out GEMM: ycomb[l] = 0.25 * sum_dir out_w[dir] @ y[dir][inv_sigma(l)]
  k_mgemm<2, 8, 0><<<dim3(128, 2), 256, 0, stream>>>(
      ybuf4, DI, w_mout, nullptr, ycombb, DI, 1024, nullptr);
  // 9. LN over 256 (bf16 in)
  k_lnb<<<B_N * LL, DI, 0, stream>>>(ycombb, normss_g, normss_b, hlnb);
  // 10. out_proj + residual(xflat)
  k_mgemm<0, 3, 0><<<dim3(128, 1), 256, 0, stream>>>(
      hlnb, DI, w_oproj, x2, nullptr, CDM, DI, xflat);
  // 11. LN2
  k_ln<CDM><<<B_N * LL, CDM, 0, stream>>>(x2, norm2_g, norm2_b, x3b);
  // 12. ffn1 + gelu
  k_mgemm<0, 4, 0><<<dim3(128, 1), 256, 0, stream>>>(
      x3b, CDM, w_ffn1, nullptr, f1b, CDM, CDM, nullptr);
  // 13. ffn2 + residual(x2)
  k_mgemm<0, 3, 0><<<dim3(128, 1), 256, 0, stream>>>(
      f1b, CDM, w_ffn2, yfin, nullptr, CDM, CDM, x2);
  // 14. tiled transpose out
  k_out_tr<<<dim3(B_N, 2, 64), 256, 0, stream>>>(yfin, (float*)d_out);
}

// Round 6
// 371.651 us; speedup vs baseline: 27.8034x; 1.0901x over previous
//
#include <hip/hip_runtime.h>
#include <math.h>

// VSSBlock on MI355X — round 5:
//  - k_conv1d4 (97us, 24%): replaced with streaming shift-register kernel
//    (each xz element read once, no LDS/barrier/shuffle).
//  - B/C projection folded into the dt GEMM as extra N columns (N=384 cat
//    weight: [dt_eff(256) ; BC(8) ; zero pad]), EPI=9 split epilogue.

#define B_N   4
#define CDM   128
#define HH    64
#define WW    64
#define LL    4096
#define DI    256
#define DS    4
#define DCV   4
#define DTR   16
#define CS    32
#define NC    (LL / CS)
#define BLT   16384          // B_N * LL

typedef float    f32x4  __attribute__((ext_vector_type(4)));
typedef __bf16   bf16x8 __attribute__((ext_vector_type(8)));

__device__ __forceinline__ float silu_f(float x) { return x / (1.f + __expf(-x)); }
__device__ __forceinline__ float softplus_f(float x) {
  return (x > 20.f) ? x : log1pf(expf(x));
}
__device__ __forceinline__ float gelu_f(float x) {
  return 0.5f * x * (1.f + erff(x * 0.70710678118654752f));
}
__device__ __forceinline__ ushort f2bf(float x) {
  unsigned u = __builtin_bit_cast(unsigned, x);
  u += 0x7fffu + ((u >> 16) & 1u);          // RNE
  return (ushort)(u >> 16);
}
__device__ __forceinline__ float bf2f(ushort u) {
  return __builtin_bit_cast(float, (unsigned)u << 16);
}

// dir-sequence position t -> original flat index l
__device__ __forceinline__ int sigma_map(int dir, int t) {
  int tt = (dir & 1) ? (LL - 1 - t) : t;
  if (dir >= 2) tt = ((tt & 63) << 6) | (tt >> 6);
  return tt;
}

// ---------------- weight fp32 -> bf16 conversion ------------------------------
__global__ void __launch_bounds__(256) k_cvt(
    const float* __restrict__ s0, const float* __restrict__ s1,
    const float* __restrict__ s2, const float* __restrict__ s3,
    const float* __restrict__ s4, const float* __restrict__ s5,
    const float* __restrict__ s6, const float* __restrict__ s7,
    ushort* __restrict__ dst)
{
  int i = (blockIdx.x * 256 + threadIdx.x) * 4;
  const float* s; int base;
  if      (i < 32768)  { s = s0; base = 0; }
  else if (i < 557056) { s = s1; base = 32768; }
  else if (i < 819200) { s = s2; base = 557056; }
  else if (i < 851968) { s = s3; base = 819200; }
  else if (i < 868352) { s = s4; base = 851968; }
  else if (i < 884736) { s = s5; base = 868352; }
  else if (i < 909312) { s = s6; base = 884736; }
  else if (i < 925696) { s = s7; base = 909312; }
  else return;
  float4 v = *(const float4*)(s + (i - base));
  dst[i+0] = f2bf(v.x); dst[i+1] = f2bf(v.y); dst[i+2] = f2bf(v.z); dst[i+3] = f2bf(v.w);
}

// ------- w_cat[dir] (384,256): rows 0..255 = dt_w @ xproj_w[:16];
//         rows 256..263 = xproj_w[16..24) (B/C proj); rows 264..383 = 0 --------
__global__ void __launch_bounds__(256) k_dteff(
    const float* __restrict__ dtw, const float* __restrict__ xpw,
    ushort* __restrict__ out)
{
  int idx = blockIdx.x * 256 + threadIdx.x;   // dir*98304 + n*256 + k
  int dir = idx / 98304; int rem = idx - dir * 98304;
  int n = rem >> 8; int k = rem & 255;
  float acc = 0.f;
  if (n < 256) {
    const float* dw = dtw + ((size_t)dir * DI + n) * DTR;
    const float* xp = xpw + (size_t)dir * 24 * DI + k;
    #pragma unroll
    for (int j = 0; j < DTR; ++j) acc += dw[j] * xp[j * DI];
  } else if (n < 264) {
    acc = xpw[(size_t)dir * 24 * DI + (size_t)(16 + n - 256) * DI + k];
  }
  out[idx] = f2bf(acc);
}

// ---------------- LN1: tiled NCHW->(B,L,C) transpose + LayerNorm --------------
__global__ void __launch_bounds__(256) k_ln1(
    const float* __restrict__ x, const float* __restrict__ g,
    const float* __restrict__ be, float* __restrict__ xflat,
    ushort* __restrict__ x1b)
{
  int blk = blockIdx.x;
  int b = blk >> 6; int l0 = (blk & 63) << 6;
  __shared__ float T[64][129];
  __shared__ float mrow[64], rrow[64];
  int t = threadIdx.x;
  int wv = t >> 6, lane = t & 63;
  for (int c = wv; c < CDM; c += 4)
    T[lane][c] = x[((size_t)b * CDM + c) * LL + l0 + lane];
  __syncthreads();
  int row = t >> 2, seg = t & 3;
  float s = 0.f;
  #pragma unroll
  for (int j = 0; j < 32; ++j) s += T[row][seg * 32 + j];
  s += __shfl_xor(s, 1); s += __shfl_xor(s, 2);
  float mean = s * (1.f / CDM);
  float v2 = 0.f;
  #pragma unroll
  for (int j = 0; j < 32; ++j) { float d = T[row][seg * 32 + j] - mean; v2 += d * d; }
  v2 += __shfl_xor(v2, 1); v2 += __shfl_xor(v2, 2);
  if (seg == 0) { mrow[row] = mean; rrow[row] = rsqrtf(v2 * (1.f / CDM) + 1e-5f); }
  __syncthreads();
  int c = t & 127;
  float gc = g[c], bc = be[c];
  for (int r = (t >> 7); r < 64; r += 2) {
    float v = T[r][c];
    size_t o = ((size_t)(b << 12) + l0 + r) * CDM + c;
    xflat[o] = v;
    x1b[o] = f2bf((v - mrow[r]) * rrow[r] * gc + bc);
  }
}

// ---------------- row LayerNorm f32 -> bf16 -----------------------------------
template<int WIDTH>
__global__ void __launch_bounds__(WIDTH) k_ln(
    const float* __restrict__ in, const float* __restrict__ g,
    const float* __restrict__ be, ushort* __restrict__ out)
{
  int row = blockIdx.x;
  int c = threadIdx.x;
  float v = in[(size_t)row * WIDTH + c];
  __shared__ float red[WIDTH];
  red[c] = v; __syncthreads();
  #pragma unroll
  for (int s = WIDTH / 2; s > 0; s >>= 1) { if (c < s) red[c] += red[c + s]; __syncthreads(); }
  float mean = red[0] * (1.f / WIDTH);
  __syncthreads();
  float dv = v - mean;
  red[c] = dv * dv; __syncthreads();
  #pragma unroll
  for (int s = WIDTH / 2; s > 0; s >>= 1) { if (c < s) red[c] += red[c + s]; __syncthreads(); }
  float var = red[0] * (1.f / WIDTH);
  out[(size_t)row * WIDTH + c] = f2bf(dv * rsqrtf(var + 1e-5f) * g[c] + be[c]);
}

// ---------------- row LayerNorm bf16 -> bf16, width 256 -----------------------
__global__ void __launch_bounds__(DI) k_lnb(
    const ushort* __restrict__ in, const float* __restrict__ g,
    const float* __restrict__ be, ushort* __restrict__ out)
{
  int row = blockIdx.x;
  int c = threadIdx.x;
  size_t off = (size_t)row * DI + c;
  float v = bf2f(in[off]);
  __shared__ float red[DI];
  red[c] = v; __syncthreads();
  #pragma unroll
  for (int s = DI / 2; s > 0; s >>= 1) { if (c < s) red[c] += red[c + s]; __syncthreads(); }
  float mean = red[0] * (1.f / DI);
  __syncthreads();
  float dv = v - mean;
  red[c] = dv * dv; __syncthreads();
  #pragma unroll
  for (int s = DI / 2; s > 0; s >>= 1) { if (c < s) red[c] += red[c + s]; __syncthreads(); }
  float var = red[0] * (1.f / DI);
  out[off] = f2bf(dv * rsqrtf(var + 1e-5f) * g[c] + be[c]);
}

// ---------------- bf16 MFMA GEMM ----------------------------------------------
// C(M,N) = A(M,K) @ Wt(N,K)^T. 128x128 tile, BK=64, 4 waves.
// GATHER: 0 none | 2 fused 4-dir out-GEMM (K=1024, inverse-sigma A rows)
// EPI: 0 f32 | 3 f32 aux+v | 4 bf16 gelu | 6 bf16 | 8 bf16 0.25*v
//      9 split: col<256 -> bf16 softplus(v+aux[col]) into Cb (ld 256);
//               256<=col<264 -> f32 v into Cf (ld 8); else skip
// BZ: 1 -> dt-GEMM batching strides (A/Cb: BLT*DI, Wt: 384*DI, Cf: BLT*8)
template<int GATHER, int EPI, int BZ>
__global__ void __launch_bounds__(256) k_mgemm(
    const ushort* __restrict__ A, int lda,
    const ushort* __restrict__ Wt,
    float* __restrict__ Cf, ushort* __restrict__ Cb,
    int ldc, int K, const float* __restrict__ aux)
{
  if (BZ) {
    int z = blockIdx.z;
    A  += (size_t)z * BLT * DI;
    Wt += (size_t)z * 384 * DI;
    if (Cb) Cb += (size_t)z * BLT * DI;
    if (Cf) Cf += (size_t)z * BLT * 8;
    if (aux) aux += (size_t)z * DI;
  }
  __shared__ ushort As[128 * 64];
  __shared__ ushort Ws[128 * 64];
  int tid = threadIdx.x;
  int m0 = blockIdx.x << 7, n0 = blockIdx.y << 7;
  int lane = tid & 63;
  int wm = ((tid >> 7) & 1) * 64;
  int wn = ((tid >> 6) & 1) * 64;
  int r15 = lane & 15, khi = lane >> 4;

  int srow = tid >> 3;
  int scol = (tid & 7) << 3;
  int arow[4];        // GATHER==0
  int arow2[4][4];    // GATHER==2: [i][dir]
  #pragma unroll
  for (int i = 0; i < 4; ++i) {
    int r = m0 + i * 32 + srow;
    if (GATHER == 2) {
      int b = r >> 12, l = r & (LL - 1);
      int tl = ((l & 63) << 6) | (l >> 6);
      arow2[i][0] = (b << 12) + l;
      arow2[i][1] = (b << 12) + (LL - 1 - l);
      arow2[i][2] = (b << 12) + tl;
      arow2[i][3] = (b << 12) + (LL - 1 - tl);
    } else arow[i] = r;
  }
  int wrow[4];
  #pragma unroll
  for (int i = 0; i < 4; ++i) wrow[i] = n0 + i * 32 + srow;

  f32x4 acc[4][4] = {};
  int wavebase = (tid & 192) * 8;

  for (int ks = 0; ks < K; ks += 64) {
    if (ks) __syncthreads();
    int dir = (GATHER == 2) ? (ks >> 8) : 0;
    int kin = (GATHER == 2) ? (ks & 255) : ks;
    #pragma unroll
    for (int i = 0; i < 4; ++i) {
      const ushort* gA = (GATHER == 2)
          ? A + (size_t)dir * (BLT * DI) + (size_t)arow2[i][dir] * DI + kin + scol
          : A + (size_t)arow[i] * lda + kin + scol;
      __builtin_amdgcn_global_load_lds(
          (const __attribute__((address_space(1))) void*)gA,
          (__attribute__((address_space(3))) void*)(As + i * 2048 + wavebase),
          16, 0, 0);
    }
    #pragma unroll
    for (int i = 0; i < 4; ++i) {
      const ushort* gW = (GATHER == 2)
          ? Wt + (size_t)dir * (DI * DI) + (size_t)wrow[i] * DI + kin + scol
          : Wt + (size_t)wrow[i] * K + kin + scol;
      __builtin_amdgcn_global_load_lds(
          (const __attribute__((address_space(1))) void*)gW,
          (__attribute__((address_space(3))) void*)(Ws + i * 2048 + wavebase),
          16, 0, 0);
    }
    __syncthreads();
    #pragma unroll
    for (int kk = 0; kk < 2; ++kk) {
      bf16x8 af[4], wf[4];
      #pragma unroll
      for (int mi = 0; mi < 4; ++mi)
        af[mi] = *(const bf16x8*)&As[(wm + mi * 16 + r15) * 64 + kk * 32 + khi * 8];
      #pragma unroll
      for (int ni = 0; ni < 4; ++ni)
        wf[ni] = *(const bf16x8*)&Ws[(wn + ni * 16 + r15) * 64 + kk * 32 + khi * 8];
      #pragma unroll
      for (int mi = 0; mi < 4; ++mi)
        #pragma unroll
        for (int ni = 0; ni < 4; ++ni)
          acc[mi][ni] = __builtin_amdgcn_mfma_f32_16x16x32_bf16(
              af[mi], wf[ni], acc[mi][ni], 0, 0, 0);
    }
  }

  #pragma unroll
  for (int mi = 0; mi < 4; ++mi) {
    #pragma unroll
    for (int j = 0; j < 4; ++j) {
      int row = m0 + wm + mi * 16 + khi * 4 + j;
      #pragma unroll
      for (int ni = 0; ni < 4; ++ni) {
        int col = n0 + wn + ni * 16 + r15;
        size_t off = (size_t)row * ldc + col;
        float v = acc[mi][ni][j];
        if      (EPI == 0) Cf[off] = v;
        else if (EPI == 3) Cf[off] = aux[off] + v;
        else if (EPI == 4) Cb[off] = f2bf(gelu_f(v));
        else if (EPI == 6) Cb[off] = f2bf(v);
        else if (EPI == 8) Cb[off] = f2bf(0.25f * v);
        else if (EPI == 9) {
          if (col < 256)      Cb[(size_t)row * 256 + col] = f2bf(softplus_f(v + aux[col]));
          else if (col < 264) Cf[(size_t)row * 8 + (col - 256)] = v;
        }
      }
    }
  }
}

// ---------------- depthwise 3x3 conv (NHWC, bf16 in) + SiLU -> bf16 -----------
__global__ void __launch_bounds__(256) k_dwconv(
    const ushort* __restrict__ h, const float* __restrict__ wgt,
    ushort* __restrict__ out)
{
  int p = blockIdx.x;
  int b = p >> 12; int l = p & (LL - 1);
  int hy = l >> 6, wx = l & 63;
  int d = threadIdx.x;
  float acc = 0.f;
  #pragma unroll
  for (int di = -1; di <= 1; ++di) {
    int yy = hy + di; if (yy < 0 || yy >= HH) continue;
    #pragma unroll
    for (int dj = -1; dj <= 1; ++dj) {
      int xx = wx + dj; if (xx < 0 || xx >= WW) continue;
      acc += wgt[d * 9 + (di + 1) * 3 + (dj + 1)] *
             bf2f(h[(((size_t)b << 12) + (yy << 6) + xx) * DI + d]);
    }
  }
  out[(size_t)p * DI + d] = f2bf(silu_f(acc));
}

// ---------------- causal conv1d + SiLU, streaming shift-register --------------
// block = 64 t of one (dir,b); thread = one d. Each xz element read once.
__global__ void __launch_bounds__(256) k_conv1d4(
    const ushort* __restrict__ xz_all, const float* __restrict__ cw,
    const float* __restrict__ cb, ushort* __restrict__ xmc4)
{
  int blk = blockIdx.x;                // dir*256 + b*64 + ch
  int dir = blk >> 8; int b = (blk >> 6) & 3; int ch = blk & 63;
  int t0 = ch << 6;
  int d = threadIdx.x;
  const float* cwd = cw + (dir * DI + d) * DCV;
  float w0 = cwd[0], w1 = cwd[1], w2 = cwd[2], w3 = cwd[3];
  float bias = cb[dir * DI + d];
  size_t colb = (size_t)(dir << 9) + d;
  size_t rowb = (size_t)(b << 12);
  float xm3 = 0.f, xm2 = 0.f, xm1 = 0.f;
  if (t0 >= 3) {
    xm3 = bf2f(xz_all[(rowb + sigma_map(dir, t0 - 3)) * 2048 + colb]);
    xm2 = bf2f(xz_all[(rowb + sigma_map(dir, t0 - 2)) * 2048 + colb]);
    xm1 = bf2f(xz_all[(rowb + sigma_map(dir, t0 - 1)) * 2048 + colb]);
  }
  size_t obase = ((size_t)dir * BLT + (b << 12) + t0) * DI + d;
  #pragma unroll 4
  for (int i = 0; i < 64; ++i) {
    int l = sigma_map(dir, t0 + i);
    float x0 = bf2f(xz_all[(rowb + l) * 2048 + colb]);
    float acc = bias + w0 * xm3 + w1 * xm2 + w2 * xm1 + w3 * x0;
    xm3 = xm2; xm2 = xm1; xm1 = x0;
    xmc4[obase + (size_t)i * DI] = f2bf(silu_f(acc));
  }
}

// ================= chunked selective scan (batched over dirs) =================
__global__ void __launch_bounds__(256) k_scan_part(
    const ushort* __restrict__ dt4, const ushort* __restrict__ xmc4,
    const float* __restrict__ xbc4, const float* __restrict__ Alog4,
    float* __restrict__ P4, float* __restrict__ H4)
{
  int blk = blockIdx.x;                  // dir*512 + b*128 + ch
  int dir = blk >> 9; int b = (blk >> 7) & 3; int ch = blk & (NC - 1);
  int d = threadIdx.x;
  const float* Alog = Alog4 + (size_t)dir * DI * DS;
  float Av[DS], h[DS], P[DS];
  #pragma unroll
  for (int n = 0; n < DS; ++n) { Av[n] = -expf(Alog[d * DS + n]); h[n] = 0.f; P[n] = 1.f; }
  size_t seg = (size_t)dir * BLT;
  size_t base = seg + (size_t)b * LL + (size_t)ch * CS;
  #pragma unroll 4
  for (int t = 0; t < CS; ++t) {
    size_t r = base + t;
    float dt = bf2f(dt4[r * DI + d]);
    float xm = bf2f(xmc4[r * DI + d]);
    float4 Bv = *(const float4*)(xbc4 + r * 8);
    float bx = dt * xm;
    float dA0 = __expf(dt * Av[0]), dA1 = __expf(dt * Av[1]);
    float dA2 = __expf(dt * Av[2]), dA3 = __expf(dt * Av[3]);
    h[0] = dA0 * h[0] + bx * Bv.x; P[0] *= dA0;
    h[1] = dA1 * h[1] + bx * Bv.y; P[1] *= dA1;
    h[2] = dA2 * h[2] + bx * Bv.z; P[2] *= dA2;
    h[3] = dA3 * h[3] + bx * Bv.w; P[3] *= dA3;
  }
  size_t o = ((size_t)blk * DI + d) * DS;
  #pragma unroll
  for (int n = 0; n < DS; ++n) { P4[o + n] = P[n]; H4[o + n] = h[n]; }
}

__global__ void __launch_bounds__(256) k_scan_carry(
    const float* __restrict__ P4, float* __restrict__ H4)
{
  int idx = blockIdx.x * 256 + threadIdx.x;   // 0 .. 16383
  int dir = idx >> 12; int r = idx & 4095;
  int b = r >> 10; int dn = r & 1023;
  size_t sbase = ((size_t)dir * 512 + (size_t)b * NC) * 1024 + dn;
  float carry = 0.f;
  #pragma unroll 8
  for (int ch = 0; ch < NC; ++ch) {
    size_t o = sbase + (size_t)ch * 1024;
    float Pv = P4[o], Hv = H4[o];
    H4[o] = carry;
    carry = Pv * carry + Hv;
  }
}

__global__ void __launch_bounds__(256) k_scan_fix(
    const ushort* __restrict__ dt4, const ushort* __restrict__ xmc4,
    const float* __restrict__ xbc4, const ushort* __restrict__ xz_all,
    const float* __restrict__ Alog4, const float* __restrict__ Dp4,
    const float* __restrict__ Cin, ushort* __restrict__ ybuf4)
{
  int blk = blockIdx.x;
  int dir = blk >> 9; int b = (blk >> 7) & 3; int ch = blk & (NC - 1);
  int d = threadIdx.x;
  const float* Alog = Alog4 + (size_t)dir * DI * DS;
  float Av[DS], h[DS];
  size_t ci = ((size_t)blk * DI + d) * DS;
  #pragma unroll
  for (int n = 0; n < DS; ++n) { Av[n] = -expf(Alog[d * DS + n]); h[n] = Cin[ci + n]; }
  float Dv = Dp4[dir * DI + d];
  size_t seg = (size_t)dir * BLT;
  size_t base = seg + (size_t)b * LL + (size_t)ch * CS;
  #pragma unroll 4
  for (int t = 0; t < CS; ++t) {
    size_t r = base + t;
    float dt = bf2f(dt4[r * DI + d]);
    float xm = bf2f(xmc4[r * DI + d]);
    float4 Bv = *(const float4*)(xbc4 + r * 8);
    float4 Cv = *(const float4*)(xbc4 + r * 8 + 4);
    float bx = dt * xm;
    float dA0 = __expf(dt * Av[0]), dA1 = __expf(dt * Av[1]);
    float dA2 = __expf(dt * Av[2]), dA3 = __expf(dt * Av[3]);
    h[0] = dA0 * h[0] + bx * Bv.x;
    h[1] = dA1 * h[1] + bx * Bv.y;
    h[2] = dA2 * h[2] + bx * Bv.z;
    h[3] = dA3 * h[3] + bx * Bv.w;
    float y = h[0] * Cv.x + h[1] * Cv.y + h[2] * Cv.z + h[3] * Cv.w;
    int l = sigma_map(dir, ch * CS + t);
    float zv = bf2f(xz_all[(((size_t)(b << 12)) + l) * 2048 + (dir << 9) + 256 + d]);
    ybuf4[r * DI + d] = f2bf((y + Dv * xm) * silu_f(zv));
  }
}

// ---------------- final (B,L,C)->(B,C,H,W) transpose, 64x64 LDS tile ----------
__global__ void __launch_bounds__(256) k_out_tr(
    const float* __restrict__ yfin, float* __restrict__ out)
{
  int b = blockIdx.x, c0 = blockIdx.y << 6, l0 = blockIdx.z << 6;
  __shared__ float T[64][65];
  int t = threadIdx.x;
  int q = t >> 6, lane = t & 63;
  for (int i = q; i < 64; i += 4)
    T[i][lane] = yfin[((size_t)(b << 12) + l0 + i) * CDM + c0 + lane];
  __syncthreads();
  for (int cc = q; cc < 64; cc += 4)
    out[(((size_t)b * CDM + c0 + cc) << 12) + l0 + lane] = T[lane][cc];
}

extern "C" void kernel_launch(void* const* d_in, const int* in_sizes, int n_in,
                              void* d_out, int out_size, void* d_ws, size_t ws_size,
                              hipStream_t stream) {
  const float* x          = (const float*)d_in[0];
  const float* norm1_g    = (const float*)d_in[1];
  const float* norm1_b    = (const float*)d_in[2];
  const float* in_proj_w  = (const float*)d_in[3];
  const float* dwconv_w   = (const float*)d_in[4];
  const float* m_in_w     = (const float*)d_in[5];
  const float* m_conv_w   = (const float*)d_in[6];
  const float* m_conv_b   = (const float*)d_in[7];
  const float* m_xproj_w  = (const float*)d_in[8];
  const float* m_dt_w     = (const float*)d_in[9];
  const float* m_dt_b     = (const float*)d_in[10];
  const float* m_A_log    = (const float*)d_in[11];
  const float* m_D        = (const float*)d_in[12];
  const float* m_out_w    = (const float*)d_in[13];
  const float* normss_g   = (const float*)d_in[14];
  const float* normss_b   = (const float*)d_in[15];
  const float* out_proj_w = (const float*)d_in[16];
  const float* norm2_g    = (const float*)d_in[17];
  const float* norm2_b    = (const float*)d_in[18];
  const float* ffn_w1     = (const float*)d_in[19];
  const float* ffn_w2     = (const float*)d_in[20];

  float* ws = (float*)d_ws;
  size_t o = 0;
  auto alloc = [&](size_t nf) { float* p = ws + o; o += nf; return p; };
  const size_t BL = BLT;
  // f32 buffers
  float* xflat = alloc(BL * CDM);
  float* x2    = alloc(BL * CDM);
  float* yfin  = alloc(BL * CDM);
  float* xbc4  = alloc(BL * 8 * 4);
  float* P4    = alloc((size_t)4 * B_N * NC * DI * DS);
  float* H4    = alloc((size_t)4 * B_N * NC * DI * DS);
  // bf16 buffers
  auto ualloc = [&](size_t nu) { ushort* p = (ushort*)(ws + o); o += (nu + 1) / 2; return p; };
  ushort* x1b    = ualloc(BL * CDM);
  ushort* hinb   = ualloc(BL * DI);
  ushort* hcb    = ualloc(BL * DI);
  ushort* xz_all = ualloc(BL * 2048);
  ushort* xmc4   = ualloc(BL * DI * 4);
  ushort* dt4    = ualloc(BL * DI * 4);
  ushort* ybuf4  = ualloc(BL * DI * 4);
  ushort* ycombb = ualloc(BL * DI);
  ushort* hlnb   = ualloc(BL * DI);
  ushort* x3b    = ualloc(BL * CDM);
  ushort* f1b    = ualloc(BL * CDM);
  ushort* wb     = ualloc(925696);
  ushort* w_cat  = ualloc((size_t)4 * 384 * DI);   // dt_eff + BC + pad
  ushort* w_inproj = wb + 0;
  ushort* w_min    = wb + 32768;      // (2048,256)
  ushort* w_mout   = wb + 557056;     // 4 x (256,256)
  ushort* w_oproj  = wb + 819200;
  ushort* w_ffn1   = wb + 851968;
  ushort* w_ffn2   = wb + 868352;

  // 0. weights -> bf16; concatenated dt/BC weight
  k_cvt<<<904, 256, 0, stream>>>(
      in_proj_w, m_in_w, m_out_w, out_proj_w, ffn_w1, ffn_w2, m_xproj_w, m_dt_w, wb);
  k_dteff<<<1536, 256, 0, stream>>>(m_dt_w, m_xproj_w, w_cat);
  // 1. tiled transpose + LN1
  k_ln1<<<B_N * 64, 256, 0, stream>>>(x, norm1_g, norm1_b, xflat, x1b);
  // 2. in_proj -> bf16
  k_mgemm<0, 6, 0><<<dim3(128, 2), 256, 0, stream>>>(
      x1b, CDM, w_inproj, nullptr, hinb, DI, CDM, nullptr);
  // 3. dw 3x3 conv + silu
  k_dwconv<<<B_N * LL, DI, 0, stream>>>(hinb, dwconv_w, hcb);
  // 4. xz for ALL dirs
  k_mgemm<0, 6, 0><<<dim3(128, 16), 256, 0, stream>>>(
      hcb, DI, w_min, nullptr, xz_all, 2048, DI, nullptr);
  // 5. conv1d (streaming), all dirs
  k_conv1d4<<<1024, 256, 0, stream>>>(xz_all, m_conv_w, m_conv_b, xmc4);
  // 6. dt + B/C GEMM (N=384 cat), batched over dirs
  k_mgemm<0, 9, 1><<<dim3(128, 3, 4), 256, 0, stream>>>(
      xmc4, DI, w_cat, xbc4, dt4, DI, DI, m_dt_b);
  // 7. chunked scan, all dirs
  k_scan_part<<<4 * B_N * NC, 256, 0, stream>>>(dt4, xmc4, xbc4, m_A_log, P4, H4);
  k_scan_carry<<<64, 256, 0, stream>>>(P4, H4);
  k_scan_fix<<<4 * B_N * NC, 256, 0, stream>>>(
      dt4, xmc4, xbc4, xz_all, m_A_log, m_D, H4, ybuf4);
  // 8. fused 4-dir out GEMM
  k_mgemm<2, 8, 0><<<dim3(128, 2), 256, 0, stream>>>(
      ybuf4, DI, w_mout, nullptr, ycombb, DI, 1024, nullptr);
  // 9. LN over 256
  k_lnb<<<B_N * LL, DI, 0, stream>>>(ycombb, normss_g, normss_b, hlnb);
  // 10. out_proj + residual(xflat)
  k_mgemm<0, 3, 0><<<dim3(128, 1), 256, 0, stream>>>(
      hlnb, DI, w_oproj, x2, nullptr, CDM, DI, xflat);
  // 11. LN2
  k_ln<CDM><<<B_N * LL, CDM, 0, stream>>>(x2, norm2_g, norm2_b, x3b);
  // 12. ffn1 + gelu
  k_mgemm<0, 4, 0><<<dim3(128, 1), 256, 0, stream>>>(
      x3b, CDM, w_ffn1, nullptr, f1b, CDM, CDM, nullptr);
  // 13. ffn2 + residual(x2)
  k_mgemm<0, 3, 0><<<dim3(128, 1), 256, 0, stream>>>(
      f1b, CDM, w_ffn2, yfin, nullptr, CDM, CDM, x2);
  // 14. tiled transpose out
  k_out_tr<<<dim3(B_N, 2, 64), 256, 0, stream>>>(yfin, (float*)d_out);
}

// Round 7
// 308.725 us; speedup vs baseline: 33.4705x; 1.2038x over previous
//
#include <hip/hip_runtime.h>
#include <math.h>

// VSSBlock on MI355X — round 6:
//  - dt GEMM epilogue (111us, VALUBusy 56%): softplus via hardware
//    v_exp/v_log instead of OCML log1pf/expf libcalls.
//  - scan_fix writes ybuf in original-l order -> out-GEMM A reads linear
//    for all dirs (was 4x over-fetch on dirs 2/3).
//  - wave-per-row LayerNorms (shuffle reduce) replace LDS-tree LNs.

#define B_N   4
#define CDM   128
#define HH    64
#define WW    64
#define LL    4096
#define DI    256
#define DS    4
#define DCV   4
#define DTR   16
#define CS    32
#define NC    (LL / CS)
#define BLT   16384          // B_N * LL

typedef float    f32x4  __attribute__((ext_vector_type(4)));
typedef __bf16   bf16x8 __attribute__((ext_vector_type(8)));

__device__ __forceinline__ float silu_f(float x) { return x / (1.f + __expf(-x)); }
// softplus = max(x,0) + log(1+exp(-|x|)); hw exp/log, err ~1e-7
__device__ __forceinline__ float softplus_f(float x) {
  return fmaxf(x, 0.f) + __logf(1.f + __expf(-fabsf(x)));
}
__device__ __forceinline__ float gelu_f(float x) {
  return 0.5f * x * (1.f + erff(x * 0.70710678118654752f));
}
__device__ __forceinline__ ushort f2bf(float x) {
  unsigned u = __builtin_bit_cast(unsigned, x);
  u += 0x7fffu + ((u >> 16) & 1u);          // RNE
  return (ushort)(u >> 16);
}
__device__ __forceinline__ float bf2f(ushort u) {
  return __builtin_bit_cast(float, (unsigned)u << 16);
}

// dir-sequence position t -> original flat index l
__device__ __forceinline__ int sigma_map(int dir, int t) {
  int tt = (dir & 1) ? (LL - 1 - t) : t;
  if (dir >= 2) tt = ((tt & 63) << 6) | (tt >> 6);
  return tt;
}

// ---------------- weight fp32 -> bf16 conversion ------------------------------
__global__ void __launch_bounds__(256) k_cvt(
    const float* __restrict__ s0, const float* __restrict__ s1,
    const float* __restrict__ s2, const float* __restrict__ s3,
    const float* __restrict__ s4, const float* __restrict__ s5,
    const float* __restrict__ s6, const float* __restrict__ s7,
    ushort* __restrict__ dst)
{
  int i = (blockIdx.x * 256 + threadIdx.x) * 4;
  const float* s; int base;
  if      (i < 32768)  { s = s0; base = 0; }
  else if (i < 557056) { s = s1; base = 32768; }
  else if (i < 819200) { s = s2; base = 557056; }
  else if (i < 851968) { s = s3; base = 819200; }
  else if (i < 868352) { s = s4; base = 851968; }
  else if (i < 884736) { s = s5; base = 868352; }
  else if (i < 909312) { s = s6; base = 884736; }
  else if (i < 925696) { s = s7; base = 909312; }
  else return;
  float4 v = *(const float4*)(s + (i - base));
  dst[i+0] = f2bf(v.x); dst[i+1] = f2bf(v.y); dst[i+2] = f2bf(v.z); dst[i+3] = f2bf(v.w);
}

// ------- w_cat[dir] (384,256): rows 0..255 = dt_w @ xproj_w[:16];
//         rows 256..263 = xproj_w[16..24); rows 264..383 = 0 ------------------
__global__ void __launch_bounds__(256) k_dteff(
    const float* __restrict__ dtw, const float* __restrict__ xpw,
    ushort* __restrict__ out)
{
  int idx = blockIdx.x * 256 + threadIdx.x;   // dir*98304 + n*256 + k
  int dir = idx / 98304; int rem = idx - dir * 98304;
  int n = rem >> 8; int k = rem & 255;
  float acc = 0.f;
  if (n < 256) {
    const float* dw = dtw + ((size_t)dir * DI + n) * DTR;
    const float* xp = xpw + (size_t)dir * 24 * DI + k;
    #pragma unroll
    for (int j = 0; j < DTR; ++j) acc += dw[j] * xp[j * DI];
  } else if (n < 264) {
    acc = xpw[(size_t)dir * 24 * DI + (size_t)(16 + n - 256) * DI + k];
  }
  out[idx] = f2bf(acc);
}

// ---------------- LN1: tiled NCHW->(B,L,C) transpose + LayerNorm --------------
__global__ void __launch_bounds__(256) k_ln1(
    const float* __restrict__ x, const float* __restrict__ g,
    const float* __restrict__ be, float* __restrict__ xflat,
    ushort* __restrict__ x1b)
{
  int blk = blockIdx.x;
  int b = blk >> 6; int l0 = (blk & 63) << 6;
  __shared__ float T[64][129];
  __shared__ float mrow[64], rrow[64];
  int t = threadIdx.x;
  int wv = t >> 6, lane = t & 63;
  for (int c = wv; c < CDM; c += 4)
    T[lane][c] = x[((size_t)b * CDM + c) * LL + l0 + lane];
  __syncthreads();
  int row = t >> 2, seg = t & 3;
  float s = 0.f;
  #pragma unroll
  for (int j = 0; j < 32; ++j) s += T[row][seg * 32 + j];
  s += __shfl_xor(s, 1); s += __shfl_xor(s, 2);
  float mean = s * (1.f / CDM);
  float v2 = 0.f;
  #pragma unroll
  for (int j = 0; j < 32; ++j) { float d = T[row][seg * 32 + j] - mean; v2 += d * d; }
  v2 += __shfl_xor(v2, 1); v2 += __shfl_xor(v2, 2);
  if (seg == 0) { mrow[row] = mean; rrow[row] = rsqrtf(v2 * (1.f / CDM) + 1e-5f); }
  __syncthreads();
  int c = t & 127;
  float gc = g[c], bc = be[c];
  for (int r = (t >> 7); r < 64; r += 2) {
    float v = T[r][c];
    size_t o = ((size_t)(b << 12) + l0 + r) * CDM + c;
    xflat[o] = v;
    x1b[o] = f2bf((v - mrow[r]) * rrow[r] * gc + bc);
  }
}

// ---------------- wave-per-row LayerNorm, width 256, bf16 in/out --------------
__global__ void __launch_bounds__(256) k_lnw256(
    const ushort* __restrict__ in, const float* __restrict__ g,
    const float* __restrict__ be, ushort* __restrict__ out)
{
  int w = threadIdx.x >> 6, lane = threadIdx.x & 63;
  int row = (blockIdx.x << 2) + w;
  size_t off = (size_t)row * DI + (lane << 2);
  ushort4 v4 = *(const ushort4*)(in + off);
  float v0 = bf2f(v4.x), v1 = bf2f(v4.y), v2 = bf2f(v4.z), v3 = bf2f(v4.w);
  float s1 = v0 + v1 + v2 + v3;
  float s2 = v0 * v0 + v1 * v1 + v2 * v2 + v3 * v3;
  #pragma unroll
  for (int o = 1; o < 64; o <<= 1) { s1 += __shfl_xor(s1, o); s2 += __shfl_xor(s2, o); }
  float mean = s1 * (1.f / DI);
  float r = rsqrtf(s2 * (1.f / DI) - mean * mean + 1e-5f);
  int c = lane << 2;
  ushort4 o4;
  o4.x = f2bf((v0 - mean) * r * g[c + 0] + be[c + 0]);
  o4.y = f2bf((v1 - mean) * r * g[c + 1] + be[c + 1]);
  o4.z = f2bf((v2 - mean) * r * g[c + 2] + be[c + 2]);
  o4.w = f2bf((v3 - mean) * r * g[c + 3] + be[c + 3]);
  *(ushort4*)(out + off) = o4;
}

// ---------------- wave-per-row LayerNorm, width 128, f32 in -> bf16 -----------
__global__ void __launch_bounds__(256) k_lnw128(
    const float* __restrict__ in, const float* __restrict__ g,
    const float* __restrict__ be, ushort* __restrict__ out)
{
  int w = threadIdx.x >> 6, lane = threadIdx.x & 63;
  int row = (blockIdx.x << 2) + w;
  size_t off = (size_t)row * CDM + (lane << 1);
  float2 v = *(const float2*)(in + off);
  float s1 = v.x + v.y;
  float s2 = v.x * v.x + v.y * v.y;
  #pragma unroll
  for (int o = 1; o < 64; o <<= 1) { s1 += __shfl_xor(s1, o); s2 += __shfl_xor(s2, o); }
  float mean = s1 * (1.f / CDM);
  float r = rsqrtf(s2 * (1.f / CDM) - mean * mean + 1e-5f);
  int c = lane << 1;
  ushort2 o2;
  o2.x = f2bf((v.x - mean) * r * g[c + 0] + be[c + 0]);
  o2.y = f2bf((v.y - mean) * r * g[c + 1] + be[c + 1]);
  *(ushort2*)(out + off) = o2;
}

// ---------------- bf16 MFMA GEMM ----------------------------------------------
// C(M,N) = A(M,K) @ Wt(N,K)^T. 128x128 tile, BK=64, 4 waves.
// GATHER: 0 none | 2 fused 4-dir out-GEMM (K=1024; A = 4 l-ordered segments
//         of 16384x256; Wt = 4 x (256,256) along K; rows linear)
// EPI: 0 f32 | 3 f32 aux+v | 4 bf16 gelu | 6 bf16 | 8 bf16 0.25*v
//      9 split: col<256 -> bf16 softplus(v+aux[col]); 256<=col<264 -> f32 v
// BZ: 1 -> dt-GEMM batching (A/Cb: BLT*DI, Wt: 384*DI, Cf: BLT*8)
template<int GATHER, int EPI, int BZ>
__global__ void __launch_bounds__(256) k_mgemm(
    const ushort* __restrict__ A, int lda,
    const ushort* __restrict__ Wt,
    float* __restrict__ Cf, ushort* __restrict__ Cb,
    int ldc, int K, const float* __restrict__ aux)
{
  if (BZ) {
    int z = blockIdx.z;
    A  += (size_t)z * BLT * DI;
    Wt += (size_t)z * 384 * DI;
    if (Cb) Cb += (size_t)z * BLT * DI;
    if (Cf) Cf += (size_t)z * BLT * 8;
    if (aux) aux += (size_t)z * DI;
  }
  __shared__ ushort As[128 * 64];
  __shared__ ushort Ws[128 * 64];
  int tid = threadIdx.x;
  int m0 = blockIdx.x << 7, n0 = blockIdx.y << 7;
  int lane = tid & 63;
  int wm = ((tid >> 7) & 1) * 64;
  int wn = ((tid >> 6) & 1) * 64;
  int r15 = lane & 15, khi = lane >> 4;

  int srow = tid >> 3;
  int scol = (tid & 7) << 3;
  int arow[4];
  #pragma unroll
  for (int i = 0; i < 4; ++i) arow[i] = m0 + i * 32 + srow;
  int wrow[4];
  #pragma unroll
  for (int i = 0; i < 4; ++i) wrow[i] = n0 + i * 32 + srow;

  f32x4 acc[4][4] = {};
  int wavebase = (tid & 192) * 8;

  for (int ks = 0; ks < K; ks += 64) {
    if (ks) __syncthreads();
    int dir = (GATHER == 2) ? (ks >> 8) : 0;
    int kin = (GATHER == 2) ? (ks & 255) : ks;
    #pragma unroll
    for (int i = 0; i < 4; ++i) {
      const ushort* gA = (GATHER == 2)
          ? A + (size_t)dir * (BLT * DI) + (size_t)arow[i] * DI + kin + scol
          : A + (size_t)arow[i] * lda + kin + scol;
      __builtin_amdgcn_global_load_lds(
          (const __attribute__((address_space(1))) void*)gA,
          (__attribute__((address_space(3))) void*)(As + i * 2048 + wavebase),
          16, 0, 0);
    }
    #pragma unroll
    for (int i = 0; i < 4; ++i) {
      const ushort* gW = (GATHER == 2)
          ? Wt + (size_t)dir * (DI * DI) + (size_t)wrow[i] * DI + kin + scol
          : Wt + (size_t)wrow[i] * K + kin + scol;
      __builtin_amdgcn_global_load_lds(
          (const __attribute__((address_space(1))) void*)gW,
          (__attribute__((address_space(3))) void*)(Ws + i * 2048 + wavebase),
          16, 0, 0);
    }
    __syncthreads();
    #pragma unroll
    for (int kk = 0; kk < 2; ++kk) {
      bf16x8 af[4], wf[4];
      #pragma unroll
      for (int mi = 0; mi < 4; ++mi)
        af[mi] = *(const bf16x8*)&As[(wm + mi * 16 + r15) * 64 + kk * 32 + khi * 8];
      #pragma unroll
      for (int ni = 0; ni < 4; ++ni)
        wf[ni] = *(const bf16x8*)&Ws[(wn + ni * 16 + r15) * 64 + kk * 32 + khi * 8];
      #pragma unroll
      for (int mi = 0; mi < 4; ++mi)
        #pragma unroll
        for (int ni = 0; ni < 4; ++ni)
          acc[mi][ni] = __builtin_amdgcn_mfma_f32_16x16x32_bf16(
              af[mi], wf[ni], acc[mi][ni], 0, 0, 0);
    }
  }

  #pragma unroll
  for (int mi = 0; mi < 4; ++mi) {
    #pragma unroll
    for (int j = 0; j < 4; ++j) {
      int row = m0 + wm + mi * 16 + khi * 4 + j;
      #pragma unroll
      for (int ni = 0; ni < 4; ++ni) {
        int col = n0 + wn + ni * 16 + r15;
        size_t off = (size_t)row * ldc + col;
        float v = acc[mi][ni][j];
        if      (EPI == 0) Cf[off] = v;
        else if (EPI == 3) Cf[off] = aux[off] + v;
        else if (EPI == 4) Cb[off] = f2bf(gelu_f(v));
        else if (EPI == 6) Cb[off] = f2bf(v);
        else if (EPI == 8) Cb[off] = f2bf(0.25f * v);
        else if (EPI == 9) {
          if (col < 256)      Cb[(size_t)row * 256 + col] = f2bf(softplus_f(v + aux[col]));
          else if (col < 264) Cf[(size_t)row * 8 + (col - 256)] = v;
        }
      }
    }
  }
}

// ---------------- depthwise 3x3 conv (NHWC, bf16 in) + SiLU -> bf16 -----------
__global__ void __launch_bounds__(256) k_dwconv(
    const ushort* __restrict__ h, const float* __restrict__ wgt,
    ushort* __restrict__ out)
{
  int p = blockIdx.x;
  int b = p >> 12; int l = p & (LL - 1);
  int hy = l >> 6, wx = l & 63;
  int d = threadIdx.x;
  float acc = 0.f;
  #pragma unroll
  for (int di = -1; di <= 1; ++di) {
    int yy = hy + di; if (yy < 0 || yy >= HH) continue;
    #pragma unroll
    for (int dj = -1; dj <= 1; ++dj) {
      int xx = wx + dj; if (xx < 0 || xx >= WW) continue;
      acc += wgt[d * 9 + (di + 1) * 3 + (dj + 1)] *
             bf2f(h[(((size_t)b << 12) + (yy << 6) + xx) * DI + d]);
    }
  }
  out[(size_t)p * DI + d] = f2bf(silu_f(acc));
}

// ---------------- causal conv1d + SiLU, streaming shift-register --------------
__global__ void __launch_bounds__(256) k_conv1d4(
    const ushort* __restrict__ xz_all, const float* __restrict__ cw,
    const float* __restrict__ cb, ushort* __restrict__ xmc4)
{
  int blk = blockIdx.x;                // dir*256 + b*64 + ch
  int dir = blk >> 8; int b = (blk >> 6) & 3; int ch = blk & 63;
  int t0 = ch << 6;
  int d = threadIdx.x;
  const float* cwd = cw + (dir * DI + d) * DCV;
  float w0 = cwd[0], w1 = cwd[1], w2 = cwd[2], w3 = cwd[3];
  float bias = cb[dir * DI + d];
  size_t colb = (size_t)(dir << 9) + d;
  size_t rowb = (size_t)(b << 12);
  float xm3 = 0.f, xm2 = 0.f, xm1 = 0.f;
  if (t0 >= 3) {
    xm3 = bf2f(xz_all[(rowb + sigma_map(dir, t0 - 3)) * 2048 + colb]);
    xm2 = bf2f(xz_all[(rowb + sigma_map(dir, t0 - 2)) * 2048 + colb]);
    xm1 = bf2f(xz_all[(rowb + sigma_map(dir, t0 - 1)) * 2048 + colb]);
  }
  size_t obase = ((size_t)dir * BLT + (b << 12) + t0) * DI + d;
  #pragma unroll 4
  for (int i = 0; i < 64; ++i) {
    int l = sigma_map(dir, t0 + i);
    float x0 = bf2f(xz_all[(rowb + l) * 2048 + colb]);
    float acc = bias + w0 * xm3 + w1 * xm2 + w2 * xm1 + w3 * x0;
    xm3 = xm2; xm2 = xm1; xm1 = x0;
    xmc4[obase + (size_t)i * DI] = f2bf(silu_f(acc));
  }
}

// ================= chunked selective scan (batched over dirs) =================
__global__ void __launch_bounds__(256) k_scan_part(
    const ushort* __restrict__ dt4, const ushort* __restrict__ xmc4,
    const float* __restrict__ xbc4, const float* __restrict__ Alog4,
    float* __restrict__ P4, float* __restrict__ H4)
{
  int blk = blockIdx.x;                  // dir*512 + b*128 + ch
  int dir = blk >> 9; int b = (blk >> 7) & 3; int ch = blk & (NC - 1);
  int d = threadIdx.x;
  const float* Alog = Alog4 + (size_t)dir * DI * DS;
  float Av[DS], h[DS], P[DS];
  #pragma unroll
  for (int n = 0; n < DS; ++n) { Av[n] = -__expf(Alog[d * DS + n]); h[n] = 0.f; P[n] = 1.f; }
  size_t seg = (size_t)dir * BLT;
  size_t base = seg + (size_t)b * LL + (size_t)ch * CS;
  #pragma unroll 4
  for (int t = 0; t < CS; ++t) {
    size_t r = base + t;
    float dt = bf2f(dt4[r * DI + d]);
    float xm = bf2f(xmc4[r * DI + d]);
    float4 Bv = *(const float4*)(xbc4 + r * 8);
    float bx = dt * xm;
    float dA0 = __expf(dt * Av[0]), dA1 = __expf(dt * Av[1]);
    float dA2 = __expf(dt * Av[2]), dA3 = __expf(dt * Av[3]);
    h[0] = dA0 * h[0] + bx * Bv.x; P[0] *= dA0;
    h[1] = dA1 * h[1] + bx * Bv.y; P[1] *= dA1;
    h[2] = dA2 * h[2] + bx * Bv.z; P[2] *= dA2;
    h[3] = dA3 * h[3] + bx * Bv.w; P[3] *= dA3;
  }
  size_t o = ((size_t)blk * DI + d) * DS;
  #pragma unroll
  for (int n = 0; n < DS; ++n) { P4[o + n] = P[n]; H4[o + n] = h[n]; }
}

__global__ void __launch_bounds__(256) k_scan_carry(
    const float* __restrict__ P4, float* __restrict__ H4)
{
  int idx = blockIdx.x * 256 + threadIdx.x;   // 0 .. 16383
  int dir = idx >> 12; int r = idx & 4095;
  int b = r >> 10; int dn = r & 1023;
  size_t sbase = ((size_t)dir * 512 + (size_t)b * NC) * 1024 + dn;
  float carry = 0.f;
  #pragma unroll 8
  for (int ch = 0; ch < NC; ++ch) {
    size_t o = sbase + (size_t)ch * 1024;
    float Pv = P4[o], Hv = H4[o];
    H4[o] = carry;
    carry = Pv * carry + Hv;
  }
}

// scan_fix: recompute from entry state; WRITE ybuf in original-l order so the
// fused out-GEMM reads linearly for all dirs.
__global__ void __launch_bounds__(256) k_scan_fix(
    const ushort* __restrict__ dt4, const ushort* __restrict__ xmc4,
    const float* __restrict__ xbc4, const ushort* __restrict__ xz_all,
    const float* __restrict__ Alog4, const float* __restrict__ Dp4,
    const float* __restrict__ Cin, ushort* __restrict__ ybuf4)
{
  int blk = blockIdx.x;
  int dir = blk >> 9; int b = (blk >> 7) & 3; int ch = blk & (NC - 1);
  int d = threadIdx.x;
  const float* Alog = Alog4 + (size_t)dir * DI * DS;
  float Av[DS], h[DS];
  size_t ci = ((size_t)blk * DI + d) * DS;
  #pragma unroll
  for (int n = 0; n < DS; ++n) { Av[n] = -__expf(Alog[d * DS + n]); h[n] = Cin[ci + n]; }
  float Dv = Dp4[dir * DI + d];
  size_t seg = (size_t)dir * BLT;
  size_t base = seg + (size_t)b * LL + (size_t)ch * CS;
  #pragma unroll 4
  for (int t = 0; t < CS; ++t) {
    size_t r = base + t;
    float dt = bf2f(dt4[r * DI + d]);
    float xm = bf2f(xmc4[r * DI + d]);
    float4 Bv = *(const float4*)(xbc4 + r * 8);
    float4 Cv = *(const float4*)(xbc4 + r * 8 + 4);
    float bx = dt * xm;
    float dA0 = __expf(dt * Av[0]), dA1 = __expf(dt * Av[1]);
    float dA2 = __expf(dt * Av[2]), dA3 = __expf(dt * Av[3]);
    h[0] = dA0 * h[0] + bx * Bv.x;
    h[1] = dA1 * h[1] + bx * Bv.y;
    h[2] = dA2 * h[2] + bx * Bv.z;
    h[3] = dA3 * h[3] + bx * Bv.w;
    float y = h[0] * Cv.x + h[1] * Cv.y + h[2] * Cv.z + h[3] * Cv.w;
    int l = sigma_map(dir, ch * CS + t);
    float zv = bf2f(xz_all[(((size_t)(b << 12)) + l) * 2048 + (dir << 9) + 256 + d]);
    ybuf4[(seg + (size_t)(b << 12) + l) * DI + d] = f2bf((y + Dv * xm) * silu_f(zv));
  }
}

// ---------------- final (B,L,C)->(B,C,H,W) transpose, 64x64 LDS tile ----------
__global__ void __launch_bounds__(256) k_out_tr(
    const float* __restrict__ yfin, float* __restrict__ out)
{
  int b = blockIdx.x, c0 = blockIdx.y << 6, l0 = blockIdx.z << 6;
  __shared__ float T[64][65];
  int t = threadIdx.x;
  int q = t >> 6, lane = t & 63;
  for (int i = q; i < 64; i += 4)
    T[i][lane] = yfin[((size_t)(b << 12) + l0 + i) * CDM + c0 + lane];
  __syncthreads();
  for (int cc = q; cc < 64; cc += 4)
    out[(((size_t)b * CDM + c0 + cc) << 12) + l0 + lane] = T[lane][cc];
}

extern "C" void kernel_launch(void* const* d_in, const int* in_sizes, int n_in,
                              void* d_out, int out_size, void* d_ws, size_t ws_size,
                              hipStream_t stream) {
  const float* x          = (const float*)d_in[0];
  const float* norm1_g    = (const float*)d_in[1];
  const float* norm1_b    = (const float*)d_in[2];
  const float* in_proj_w  = (const float*)d_in[3];
  const float* dwconv_w   = (const float*)d_in[4];
  const float* m_in_w     = (const float*)d_in[5];
  const float* m_conv_w   = (const float*)d_in[6];
  const float* m_conv_b   = (const float*)d_in[7];
  const float* m_xproj_w  = (const float*)d_in[8];
  const float* m_dt_w     = (const float*)d_in[9];
  const float* m_dt_b     = (const float*)d_in[10];
  const float* m_A_log    = (const float*)d_in[11];
  const float* m_D        = (const float*)d_in[12];
  const float* m_out_w    = (const float*)d_in[13];
  const float* normss_g   = (const float*)d_in[14];
  const float* normss_b   = (const float*)d_in[15];
  const float* out_proj_w = (const float*)d_in[16];
  const float* norm2_g    = (const float*)d_in[17];
  const float* norm2_b    = (const float*)d_in[18];
  const float* ffn_w1     = (const float*)d_in[19];
  const float* ffn_w2     = (const float*)d_in[20];

  float* ws = (float*)d_ws;
  size_t o = 0;
  auto alloc = [&](size_t nf) { float* p = ws + o; o += nf; return p; };
  const size_t BL = BLT;
  // f32 buffers
  float* xflat = alloc(BL * CDM);
  float* x2    = alloc(BL * CDM);
  float* yfin  = alloc(BL * CDM);
  float* xbc4  = alloc(BL * 8 * 4);
  float* P4    = alloc((size_t)4 * B_N * NC * DI * DS);
  float* H4    = alloc((size_t)4 * B_N * NC * DI * DS);
  // bf16 buffers
  auto ualloc = [&](size_t nu) { ushort* p = (ushort*)(ws + o); o += (nu + 1) / 2; return p; };
  ushort* x1b    = ualloc(BL * CDM);
  ushort* hinb   = ualloc(BL * DI);
  ushort* hcb    = ualloc(BL * DI);
  ushort* xz_all = ualloc(BL * 2048);
  ushort* xmc4   = ualloc(BL * DI * 4);
  ushort* dt4    = ualloc(BL * DI * 4);
  ushort* ybuf4  = ualloc(BL * DI * 4);
  ushort* ycombb = ualloc(BL * DI);
  ushort* hlnb   = ualloc(BL * DI);
  ushort* x3b    = ualloc(BL * CDM);
  ushort* f1b    = ualloc(BL * CDM);
  ushort* wb     = ualloc(925696);
  ushort* w_cat  = ualloc((size_t)4 * 384 * DI);   // dt_eff + BC + pad
  ushort* w_inproj = wb + 0;
  ushort* w_min    = wb + 32768;      // (2048,256)
  ushort* w_mout   = wb + 557056;     // 4 x (256,256)
  ushort* w_oproj  = wb + 819200;
  ushort* w_ffn1   = wb + 851968;
  ushort* w_ffn2   = wb + 868352;

  // 0. weights -> bf16; concatenated dt/BC weight
  k_cvt<<<904, 256, 0, stream>>>(
      in_proj_w, m_in_w, m_out_w, out_proj_w, ffn_w1, ffn_w2, m_xproj_w, m_dt_w, wb);
  k_dteff<<<1536, 256, 0, stream>>>(m_dt_w, m_xproj_w, w_cat);
  // 1. tiled transpose + LN1
  k_ln1<<<B_N * 64, 256, 0, stream>>>(x, norm1_g, norm1_b, xflat, x1b);
  // 2. in_proj -> bf16
  k_mgemm<0, 6, 0><<<dim3(128, 2), 256, 0, stream>>>(
      x1b, CDM, w_inproj, nullptr, hinb, DI, CDM, nullptr);
  // 3. dw 3x3 conv + silu
  k_dwconv<<<B_N * LL, DI, 0, stream>>>(hinb, dwconv_w, hcb);
  // 4. xz for ALL dirs
  k_mgemm<0, 6, 0><<<dim3(128, 16), 256, 0, stream>>>(
      hcb, DI, w_min, nullptr, xz_all, 2048, DI, nullptr);
  // 5. conv1d (streaming), all dirs
  k_conv1d4<<<1024, 256, 0, stream>>>(xz_all, m_conv_w, m_conv_b, xmc4);
  // 6. dt + B/C GEMM (N=384 cat), batched over dirs
  k_mgemm<0, 9, 1><<<dim3(128, 3, 4), 256, 0, stream>>>(
      xmc4, DI, w_cat, xbc4, dt4, DI, DI, m_dt_b);
  // 7. chunked scan, all dirs
  k_scan_part<<<4 * B_N * NC, 256, 0, stream>>>(dt4, xmc4, xbc4, m_A_log, P4, H4);
  k_scan_carry<<<64, 256, 0, stream>>>(P4, H4);
  k_scan_fix<<<4 * B_N * NC, 256, 0, stream>>>(
      dt4, xmc4, xbc4, xz_all, m_A_log, m_D, H4, ybuf4);
  // 8. fused 4-dir out GEMM (A now linear in l for all dirs)
  k_mgemm<2, 8, 0><<<dim3(128, 2), 256, 0, stream>>>(
      ybuf4, DI, w_mout, nullptr, ycombb, DI, 1024, nullptr);
  // 9. LN over 256 (wave-per-row)
  k_lnw256<<<BLT / 4, 256, 0, stream>>>(ycombb, normss_g, normss_b, hlnb);
  // 10. out_proj + residual(xflat)
  k_mgemm<0, 3, 0><<<dim3(128, 1), 256, 0, stream>>>(
      hlnb, DI, w_oproj, x2, nullptr, CDM, DI, xflat);
  // 11. LN2 (wave-per-row)
  k_lnw128<<<BLT / 4, 256, 0, stream>>>(x2, norm2_g, norm2_b, x3b);
  // 12. ffn1 + gelu
  k_mgemm<0, 4, 0><<<dim3(128, 1), 256, 0, stream>>>(
      x3b, CDM, w_ffn1, nullptr, f1b, CDM, CDM, nullptr);
  // 13. ffn2 + residual(x2)
  k_mgemm<0, 3, 0><<<dim3(128, 1), 256, 0, stream>>>(
      f1b, CDM, w_ffn2, yfin, nullptr, CDM, CDM, x2);
  // 14. tiled transpose out
  k_out_tr<<<dim3(B_N, 2, 64), 256, 0, stream>>>(yfin, (float*)d_out);
}